// Round 3
// baseline (524.632 us; speedup 1.0000x reference)
//
#include <hip/hip_runtime.h>
#include <hip/hip_bf16.h>

typedef __attribute__((ext_vector_type(8))) short short8;
typedef __attribute__((ext_vector_type(4))) float f32x4;

#define DEVFN static __device__ __forceinline__

DEVFN float bf2f(unsigned short u) {
    unsigned int i = ((unsigned int)u) << 16;
    float f; __builtin_memcpy(&f, &i, 4); return f;
}
DEVFN unsigned short f2bf(float f) {
    unsigned int i; __builtin_memcpy(&i, &f, 4);
    unsigned int r = i + 0x7fffu + ((i >> 16) & 1u);
    return (unsigned short)(r >> 16);
}

DEVFN void load_lds16(const void* g, void* l) {
    __builtin_amdgcn_global_load_lds(
        (__attribute__((address_space(1))) void*)g,
        (__attribute__((address_space(3))) void*)l, 16, 0, 0);
}

// ---------------- constants ----------------
constexpr int Bsz = 2, T = 2048, C = 1024;
constexpr int NH = 16, NKV = 8, HD = 64;
constexpr int HID = 4096;
constexpr int NTOK = Bsz * T;              // 4096
constexpr size_t MiB = 1024 * 1024;

// workspace offsets (bytes)
constexpr size_t OFF_WQKV = 0;             // bf16 [2048][1024]   4 MiB
constexpr size_t OFF_WOUT = 4 * MiB;       // bf16 [1024][1024]   2 MiB
constexpr size_t OFF_WGATE = 6 * MiB;      // bf16 [4096][1024]   8 MiB
constexpr size_t OFF_WUP = 14 * MiB;       // bf16 [4096][1024]   8 MiB
constexpr size_t OFF_WDOWN = 22 * MiB;     // bf16 [1024][4096]   8 MiB
constexpr size_t OFF_XN1 = 30 * MiB;       // bf16 [4096][1024]   8 MiB
constexpr size_t OFF_QKVB = 38 * MiB;      // bf16 [4096][2048]  16 MiB (dead after rope/vtrans)
constexpr size_t OFF_P2 = 38 * MiB;        // bf16 4x[4096][1024] 32 MiB (out-proj partials; reuses QKVB)
constexpr size_t OFF_P4 = 30 * MiB;        // bf16 4x[4096][1024] 32 MiB (down partials; xn1/p2 dead by then)
constexpr size_t OFF_QB = 70 * MiB;        // bf16 [2][16][2048][64] 8 MiB
constexpr size_t OFF_KB = 78 * MiB;        // bf16 [2][8][2048][64]  4 MiB
constexpr size_t OFF_VT = 82 * MiB;        // bf16 [2][8][64][2048]  4 MiB
constexpr size_t OFF_CTX = 86 * MiB;       // bf16 [4096][1024]   8 MiB
constexpr size_t OFF_X2 = 94 * MiB;        // f32  [4096][1024]  16 MiB
constexpr size_t OFF_XN2 = 110 * MiB;      // bf16 [4096][1024]   8 MiB
constexpr size_t OFF_G = 118 * MiB;        // bf16 [4096][4096]  32 MiB
// total 150 MiB

// ---------------- merged weight cast + transpose: in[K][N] f32 -> out[N][K] bf16 ----------------
// all 7 weights in one launch; 15360 blocks of 32x32 tiles
__global__ __launch_bounds__(256) void transpose_all(
    const float* __restrict__ qk, const float* __restrict__ kk2,
    const float* __restrict__ vk, const float* __restrict__ ok,
    const float* __restrict__ gk, const float* __restrict__ uk,
    const float* __restrict__ dk,
    unsigned short* __restrict__ wqkv, unsigned short* __restrict__ wout,
    unsigned short* __restrict__ wgate, unsigned short* __restrict__ wup,
    unsigned short* __restrict__ wdown) {
    __shared__ float t[32][33];
    int id = blockIdx.x;
    const float* in; unsigned short* out; int K, N, nx, base;
    if (id < 1024)       { in = qk;  out = wqkv;                        K = 1024; N = 1024; nx = 32;  base = 0; }
    else if (id < 1536)  { in = kk2; out = wqkv + (size_t)1024 * 1024;  K = 1024; N = 512;  nx = 16;  base = 1024; }
    else if (id < 2048)  { in = vk;  out = wqkv + (size_t)1536 * 1024;  K = 1024; N = 512;  nx = 16;  base = 1536; }
    else if (id < 3072)  { in = ok;  out = wout;                        K = 1024; N = 1024; nx = 32;  base = 2048; }
    else if (id < 7168)  { in = gk;  out = wgate;                       K = 1024; N = 4096; nx = 128; base = 3072; }
    else if (id < 11264) { in = uk;  out = wup;                         K = 1024; N = 4096; nx = 128; base = 7168; }
    else                 { in = dk;  out = wdown;                       K = 4096; N = 1024; nx = 32;  base = 11264; }
    int lid = id - base;
    int n0 = (lid % nx) * 32, k0 = (lid / nx) * 32;
    int tx = threadIdx.x & 31, ty = threadIdx.x >> 5;
#pragma unroll
    for (int i = 0; i < 4; i++)
        t[ty + 8 * i][tx] = in[(size_t)(k0 + ty + 8 * i) * N + n0 + tx];
    __syncthreads();
#pragma unroll
    for (int i = 0; i < 4; i++)
        out[(size_t)(n0 + ty + 8 * i) * K + k0 + tx] = f2bf(t[tx][ty + 8 * i]);
}

// ---------------- RMS norm: f32 [rows][1024] -> bf16, *(1+scale) ----------------
__global__ __launch_bounds__(256) void rms_kernel(const float* __restrict__ in,
                                                  const float* __restrict__ scale,
                                                  unsigned short* __restrict__ out) {
    __shared__ float red[4];
    int row = blockIdx.x, tid = threadIdx.x;
    const float4 v = *(const float4*)&in[(size_t)row * 1024 + tid * 4];
    float ss = v.x * v.x + v.y * v.y + v.z * v.z + v.w * v.w;
#pragma unroll
    for (int m = 32; m; m >>= 1) ss += __shfl_xor(ss, m, 64);
    if ((tid & 63) == 0) red[tid >> 6] = ss;
    __syncthreads();
    float tot = red[0] + red[1] + red[2] + red[3];
    float inv = rsqrtf(tot * (1.f / 1024.f) + 1e-6f);
    const float4 sc = *(const float4*)&scale[tid * 4];
    size_t o = (size_t)row * 1024 + tid * 4;
    out[o + 0] = f2bf(v.x * inv * (1.f + sc.x));
    out[o + 1] = f2bf(v.y * inv * (1.f + sc.y));
    out[o + 2] = f2bf(v.z * inv * (1.f + sc.z));
    out[o + 3] = f2bf(v.w * inv * (1.f + sc.w));
}

// ---------------- GEMM: C[M][N](+z) = A[M][K] @ Bt[N][K]^T, bf16 in, fp32 acc ----------------
// LDS layout == MFMA fragment layout: 16-row groups, chunk-major, so fragment
// reads are ds_read_b128 at group*1024B + lane*16B (conflict-free).
// EPI: 0 = fp32 store; 4 = bf16 store. blockIdx.z selects K-slice.
template <int EPI>
__global__ __launch_bounds__(256) void gemm128(const unsigned short* __restrict__ A,
                                               const unsigned short* __restrict__ Bt,
                                               void* __restrict__ Cp,
                                               int N, int K, int lda, int ldb,
                                               size_t zA, size_t zB, size_t zC) {
    __shared__ __align__(16) unsigned short As[128 * 32];
    __shared__ __align__(16) unsigned short Bs[128 * 32];
    A += (size_t)blockIdx.z * zA;
    Bt += (size_t)blockIdx.z * zB;
    const int tid = threadIdx.x;
    const int lane = tid & 63, w = tid >> 6;
    const int quad = lane >> 4, l15 = lane & 15;
    const int wr = w >> 1, wc = w & 1;
    const int m0 = blockIdx.y * 128, n0 = blockIdx.x * 128;

    f32x4 acc[4][4];
#pragma unroll
    for (int i = 0; i < 4; i++)
#pragma unroll
        for (int j = 0; j < 4; j++) acc[i][j] = f32x4{0.f, 0.f, 0.f, 0.f};

    const int sRow = l15;               // row within 16-row group
    const int sChunk = quad << 3;       // k-offset (elements)

    for (int kk = 0; kk < K; kk += 32) {
#pragma unroll
        for (int i = 0; i < 2; i++) {
            // wave w stages rows [i*64 + w*16, +16) -> group i*4+w, lane l at group*512 + l*8 shorts
            load_lds16(A + (size_t)(m0 + (i << 6) + (w << 4) + sRow) * lda + kk + sChunk,
                       &As[((i << 2) + w) * 512]);
            load_lds16(Bt + (size_t)(n0 + (i << 6) + (w << 4) + sRow) * ldb + kk + sChunk,
                       &Bs[((i << 2) + w) * 512]);
        }
        __syncthreads();
        short8 a[4], b[4];
#pragma unroll
        for (int mi = 0; mi < 4; mi++)
            a[mi] = *(const short8*)&As[(wr * 4 + mi) * 512 + lane * 8];
#pragma unroll
        for (int ni = 0; ni < 4; ni++)
            b[ni] = *(const short8*)&Bs[(wc * 4 + ni) * 512 + lane * 8];
#pragma unroll
        for (int mi = 0; mi < 4; mi++)
#pragma unroll
            for (int ni = 0; ni < 4; ni++)
                acc[mi][ni] = __builtin_amdgcn_mfma_f32_16x16x32_bf16(a[mi], b[ni], acc[mi][ni], 0, 0, 0);
        __syncthreads();
    }
#pragma unroll
    for (int mi = 0; mi < 4; mi++) {
#pragma unroll
        for (int ni = 0; ni < 4; ni++) {
#pragma unroll
            for (int r = 0; r < 4; r++) {
                int row = m0 + wr * 64 + mi * 16 + quad * 4 + r;
                int col = n0 + wc * 64 + ni * 16 + l15;
                size_t idx = (size_t)blockIdx.z * zC + (size_t)row * N + col;
                float v = acc[mi][ni][r];
                if constexpr (EPI == 0) {
                    ((float*)Cp)[idx] = v;
                } else {
                    ((unsigned short*)Cp)[idx] = f2bf(v);
                }
            }
        }
    }
}

// ---------------- fused gate+up GEMM: 128x64 tile of BOTH gate and up, epilogue silu(g)*u ----------------
__global__ __launch_bounds__(256) void gateup_kernel(const unsigned short* __restrict__ A,
                                                     const unsigned short* __restrict__ Bg,
                                                     const unsigned short* __restrict__ Bu,
                                                     unsigned short* __restrict__ out) {
    __shared__ __align__(16) unsigned short As[128 * 32];
    __shared__ __align__(16) unsigned short Gs[64 * 32];
    __shared__ __align__(16) unsigned short Us[64 * 32];
    const int tid = threadIdx.x;
    const int lane = tid & 63, w = tid >> 6;
    const int quad = lane >> 4, l15 = lane & 15;
    const int wr = w >> 1, wc = w & 1;
    const int m0 = blockIdx.y * 128, n0 = blockIdx.x * 64;

    f32x4 aG[4][2], aU[4][2];
#pragma unroll
    for (int i = 0; i < 4; i++)
#pragma unroll
        for (int j = 0; j < 2; j++) { aG[i][j] = f32x4{0.f, 0.f, 0.f, 0.f}; aU[i][j] = f32x4{0.f, 0.f, 0.f, 0.f}; }

    const int sRow = l15;
    const int sChunk = quad << 3;

    for (int kk = 0; kk < 1024; kk += 32) {
#pragma unroll
        for (int i = 0; i < 2; i++)
            load_lds16(A + (size_t)(m0 + (i << 6) + (w << 4) + sRow) * 1024 + kk + sChunk,
                       &As[((i << 2) + w) * 512]);
        load_lds16(Bg + (size_t)(n0 + (w << 4) + sRow) * 1024 + kk + sChunk, &Gs[w * 512]);
        load_lds16(Bu + (size_t)(n0 + (w << 4) + sRow) * 1024 + kk + sChunk, &Us[w * 512]);
        __syncthreads();
        short8 a[4], bg[2], bu[2];
#pragma unroll
        for (int mi = 0; mi < 4; mi++)
            a[mi] = *(const short8*)&As[(wr * 4 + mi) * 512 + lane * 8];
#pragma unroll
        for (int ni = 0; ni < 2; ni++) {
            bg[ni] = *(const short8*)&Gs[(wc * 2 + ni) * 512 + lane * 8];
            bu[ni] = *(const short8*)&Us[(wc * 2 + ni) * 512 + lane * 8];
        }
#pragma unroll
        for (int mi = 0; mi < 4; mi++)
#pragma unroll
            for (int ni = 0; ni < 2; ni++) {
                aG[mi][ni] = __builtin_amdgcn_mfma_f32_16x16x32_bf16(a[mi], bg[ni], aG[mi][ni], 0, 0, 0);
                aU[mi][ni] = __builtin_amdgcn_mfma_f32_16x16x32_bf16(a[mi], bu[ni], aU[mi][ni], 0, 0, 0);
            }
        __syncthreads();
    }
#pragma unroll
    for (int mi = 0; mi < 4; mi++)
#pragma unroll
        for (int ni = 0; ni < 2; ni++)
#pragma unroll
            for (int r = 0; r < 4; r++) {
                int row = m0 + wr * 64 + mi * 16 + quad * 4 + r;
                int col = n0 + wc * 32 + ni * 16 + l15;
                float vg = aG[mi][ni][r], vu = aU[mi][ni][r];
                float s = vg / (1.f + __expf(-vg));
                out[(size_t)row * 4096 + col] = f2bf(s * vu);
            }
}

// ---------------- out-proj reduce: x2 = sum(p[0..3]) + x; xn2 = rms(x2)*(1+scale) ----------------
__global__ __launch_bounds__(256) void reduce_out(const unsigned short* __restrict__ p,
                                                  const float* __restrict__ x,
                                                  const float* __restrict__ scale,
                                                  float* __restrict__ x2,
                                                  unsigned short* __restrict__ xn2) {
    __shared__ float red[4];
    int row = blockIdx.x, tid = threadIdx.x;
    size_t base = (size_t)row * 1024 + tid * 4;
    const size_t Z = (size_t)NTOK * 1024;
    float4 v = *(const float4*)&x[base];
#pragma unroll
    for (int z = 0; z < 4; z++) {
        ushort4 u = *(const ushort4*)&p[base + z * Z];
        v.x += bf2f(u.x); v.y += bf2f(u.y); v.z += bf2f(u.z); v.w += bf2f(u.w);
    }
    *(float4*)&x2[base] = v;
    float ss = v.x * v.x + v.y * v.y + v.z * v.z + v.w * v.w;
#pragma unroll
    for (int m = 32; m; m >>= 1) ss += __shfl_xor(ss, m, 64);
    if ((tid & 63) == 0) red[tid >> 6] = ss;
    __syncthreads();
    float tot = red[0] + red[1] + red[2] + red[3];
    float inv = rsqrtf(tot * (1.f / 1024.f) + 1e-6f);
    const float4 sc = *(const float4*)&scale[tid * 4];
    xn2[base + 0] = f2bf(v.x * inv * (1.f + sc.x));
    xn2[base + 1] = f2bf(v.y * inv * (1.f + sc.y));
    xn2[base + 2] = f2bf(v.z * inv * (1.f + sc.z));
    xn2[base + 3] = f2bf(v.w * inv * (1.f + sc.w));
}

// ---------------- down reduce: out = sum(p[0..3]) + x2, fused kurtosis ----------------
__global__ __launch_bounds__(256) void reduce_down(const unsigned short* __restrict__ p,
                                                   const float* __restrict__ x2,
                                                   float* __restrict__ outx,
                                                   float* __restrict__ outk) {
    __shared__ float red[4], r2[4], r4[4];
    int row = blockIdx.x, tid = threadIdx.x;
    size_t base = (size_t)row * 1024 + tid * 4;
    const size_t Z = (size_t)NTOK * 1024;
    float4 v = *(const float4*)&x2[base];
#pragma unroll
    for (int z = 0; z < 4; z++) {
        ushort4 u = *(const ushort4*)&p[base + z * Z];
        v.x += bf2f(u.x); v.y += bf2f(u.y); v.z += bf2f(u.z); v.w += bf2f(u.w);
    }
    *(float4*)&outx[base] = v;
    float s = v.x + v.y + v.z + v.w;
#pragma unroll
    for (int m = 32; m; m >>= 1) s += __shfl_xor(s, m, 64);
    if ((tid & 63) == 0) red[tid >> 6] = s;
    __syncthreads();
    float mean = (red[0] + red[1] + red[2] + red[3]) * (1.f / 1024.f);
    float cx = v.x - mean, cy = v.y - mean, cz = v.z - mean, cw = v.w - mean;
    float x2v = cx * cx, y2 = cy * cy, z2 = cz * cz, w2 = cw * cw;
    float c2 = x2v + y2 + z2 + w2;
    float c4 = x2v * x2v + y2 * y2 + z2 * z2 + w2 * w2;
#pragma unroll
    for (int m = 32; m; m >>= 1) {
        c2 += __shfl_xor(c2, m, 64);
        c4 += __shfl_xor(c4, m, 64);
    }
    if ((tid & 63) == 0) { r2[tid >> 6] = c2; r4[tid >> 6] = c4; }
    __syncthreads();
    if (tid == 0) {
        float m2 = (r2[0] + r2[1] + r2[2] + r2[3]) * (1.f / 1024.f);
        float m4 = (r4[0] + r4[1] + r4[2] + r4[3]) * (1.f / 1024.f);
        float kurt = m4 / (m2 * m2 + 1e-6f) - 3.f;
        if (kurt > 0.f) atomicAdd(outk, kurt);
    }
}

// ---------------- RoPE scatter: qkvb bf16 [tok][2048] -> qb/kb bf16 head-major ----------------
__global__ __launch_bounds__(256) void rope_kernel(const unsigned short* __restrict__ qkvb,
                                                   unsigned short* __restrict__ qb,
                                                   unsigned short* __restrict__ kb) {
    __shared__ float sv[32], cv[32];
    int tok = blockIdx.x;
    int b = tok >> 11, t = tok & 2047;
    int tid = threadIdx.x;
    if (tid < 32) {
        float fr = (float)tid * (1.f / 32.f);
        float freq = powf(1e6f, -fr);
        float a = (float)t * freq;
        sv[tid] = sinf(a);
        cv[tid] = cosf(a);
    }
    __syncthreads();
    const unsigned short* rowp = qkvb + (size_t)tok * 2048;
#pragma unroll
    for (int e = tid; e < 1536; e += 256) {
        int u = e >> 6, d = e & 63;
        int col = (u < 16) ? (u * 64 + d) : (1024 + (u - 16) * 64 + d);
        int pcol = (d < 32) ? col + 32 : col - 32;
        float sgn = (d < 32) ? -1.f : 1.f;
        float o = bf2f(rowp[col]) * cv[d & 31] + sgn * bf2f(rowp[pcol]) * sv[d & 31];
        if (u < 16)
            qb[((size_t)(b * 16 + u) * 2048 + t) * 64 + d] = f2bf(o);
        else
            kb[((size_t)(b * 8 + (u - 16)) * 2048 + t) * 64 + d] = f2bf(o);
    }
}

// ---------------- V transpose: qkvb v-cols -> vt bf16 [b][h][64 d][2048 t] ----------------
__global__ __launch_bounds__(256) void vtrans_kernel(const unsigned short* __restrict__ qkvb,
                                                     unsigned short* __restrict__ vt) {
    __shared__ unsigned short tile[64][68];
    int t0 = blockIdx.x * 64, h = blockIdx.y, b = blockIdx.z;
    int tid = threadIdx.x;
    int d = tid & 63, tr = tid >> 6;
#pragma unroll
    for (int i = 0; i < 16; i++) {
        int t = tr + i * 4;
        tile[t][d] = qkvb[(size_t)(b * 2048 + t0 + t) * 2048 + 1536 + h * 64 + d];
    }
    __syncthreads();
    int tt = tid & 63, dr = tid >> 6;
#pragma unroll
    for (int i = 0; i < 16; i++) {
        int dd = dr + i * 4;
        vt[((size_t)(b * 8 + h) * 64 + dd) * 2048 + t0 + tt] = tile[tt][dd];
    }
}

// ---------------- flash attention, sliding window, soft cap ----------------
__global__ __launch_bounds__(256) void attn_kernel(const unsigned short* __restrict__ qb,
                                                   const unsigned short* __restrict__ kb,
                                                   const unsigned short* __restrict__ vt,
                                                   unsigned short* __restrict__ ctx) {
    __shared__ __align__(16) unsigned short P[4][16 * 32];
    const int tid = threadIdx.x, lane = tid & 63, w = tid >> 6;
    const int quad = lane >> 4, l15 = lane & 15;
    const int qt = blockIdx.x, H = blockIdx.y, b = blockIdx.z;
    const int hkv = H & 7;
    const int qw = qt * 64 + w * 16;

    const unsigned short* qbase = qb + ((size_t)(b * 16 + H) * 2048 + qw) * 64;
    short8 aq0 = *(const short8*)(qbase + (size_t)l15 * 64 + quad * 8);
    short8 aq1 = *(const short8*)(qbase + (size_t)l15 * 64 + 32 + quad * 8);

    const unsigned short* kbase = kb + (size_t)(b * 8 + hkv) * 2048 * 64;
    const unsigned short* vbase = vt + (size_t)(b * 8 + hkv) * 64 * 2048;

    f32x4 O[4];
#pragma unroll
    for (int i = 0; i < 4; i++) O[i] = f32x4{0.f, 0.f, 0.f, 0.f};
    float mrow[4], lrow[4];
#pragma unroll
    for (int r = 0; r < 4; r++) { mrow[r] = -1e30f; lrow[r] = 0.f; }

    int kstart = qw - 511;
    if (kstart < 0) kstart = 0;
    kstart &= ~31;
    unsigned short* Pw = P[w];

    for (int k0 = kstart; k0 <= qw + 15; k0 += 32) {
        f32x4 S[2];
#pragma unroll
        for (int c = 0; c < 2; c++) {
            const unsigned short* kp = kbase + (size_t)(k0 + c * 16 + l15) * 64 + quad * 8;
            short8 kf0 = *(const short8*)kp;
            short8 kf1 = *(const short8*)(kp + 32);
            f32x4 s = __builtin_amdgcn_mfma_f32_16x16x32_bf16(aq0, kf0, f32x4{0.f, 0.f, 0.f, 0.f}, 0, 0, 0);
            s = __builtin_amdgcn_mfma_f32_16x16x32_bf16(aq1, kf1, s, 0, 0, 0);
            S[c] = s;
        }
        float y[2][4];
#pragma unroll
        for (int c = 0; c < 2; c++)
#pragma unroll
            for (int r = 0; r < 4; r++) {
                int i = qw + quad * 4 + r;
                int j = k0 + c * 16 + l15;
                float x = S[c][r] * 0.125f;
                float tt = x * 0.02f;
                tt = fminf(8.f, fmaxf(-8.f, tt));
                float e = __expf(2.f * tt);
                float yv = 50.f * (e - 1.f) / (e + 1.f);
                y[c][r] = (j <= i && (i - j) < 512) ? yv : -__builtin_inff();
            }
        float p[2][4], alpha[4];
#pragma unroll
        for (int r = 0; r < 4; r++) {
            float v = fmaxf(y[0][r], y[1][r]);
#pragma unroll
            for (int mm = 8; mm; mm >>= 1) v = fmaxf(v, __shfl_xor(v, mm, 16));
            float mnew = fmaxf(mrow[r], v);
            alpha[r] = __expf(mrow[r] - mnew);
            float p0 = __expf(y[0][r] - mnew);
            float p1 = __expf(y[1][r] - mnew);
            p[0][r] = p0; p[1][r] = p1;
            float rs = p0 + p1;
#pragma unroll
            for (int mm = 8; mm; mm >>= 1) rs += __shfl_xor(rs, mm, 16);
            lrow[r] = lrow[r] * alpha[r] + rs;
            mrow[r] = mnew;
        }
#pragma unroll
        for (int c = 0; c < 2; c++)
#pragma unroll
            for (int r = 0; r < 4; r++)
                Pw[(quad * 4 + r) * 32 + c * 16 + l15] = f2bf(p[c][r]);
        asm volatile("s_waitcnt lgkmcnt(0)" ::: "memory");
        short8 pf = *(const short8*)&Pw[l15 * 32 + quad * 8];
#pragma unroll
        for (int ni = 0; ni < 4; ni++) {
            short8 vf = *(const short8*)(vbase + (size_t)(ni * 16 + l15) * 2048 + k0 + quad * 8);
            f32x4 o = O[ni];
#pragma unroll
            for (int r = 0; r < 4; r++) o[r] *= alpha[r];
            O[ni] = __builtin_amdgcn_mfma_f32_16x16x32_bf16(pf, vf, o, 0, 0, 0);
        }
        asm volatile("s_waitcnt lgkmcnt(0)" ::: "memory");
    }
#pragma unroll
    for (int r = 0; r < 4; r++) {
        float inv = 1.f / lrow[r];
        int i = qw + quad * 4 + r;
        size_t tok = (size_t)b * 2048 + i;
#pragma unroll
        for (int ni = 0; ni < 4; ni++)
            ctx[tok * 1024 + H * 64 + ni * 16 + l15] = f2bf(O[ni][r] * inv);
    }
}

// ---------------- kurtosis init ----------------
__global__ void kurt_init(float* dst, const float* ksum) { dst[0] = ksum[0]; }

// ---------------- launch ----------------
extern "C" void kernel_launch(void* const* d_in, const int* in_sizes, int n_in,
                              void* d_out, int out_size, void* d_ws, size_t ws_size,
                              hipStream_t stream) {
    const float* x = (const float*)d_in[0];
    const float* ksum = (const float*)d_in[1];
    const float* rms1_scale = (const float*)d_in[2];
    const float* q_kernel = (const float*)d_in[3];
    const float* k_kernel = (const float*)d_in[4];
    const float* v_kernel = (const float*)d_in[5];
    const float* out_kernel = (const float*)d_in[6];
    const float* rms2_scale = (const float*)d_in[7];
    const float* gate_kernel = (const float*)d_in[8];
    const float* up_kernel = (const float*)d_in[9];
    const float* down_kernel = (const float*)d_in[10];

    char* ws = (char*)d_ws;
    unsigned short* wqkv = (unsigned short*)(ws + OFF_WQKV);
    unsigned short* wout = (unsigned short*)(ws + OFF_WOUT);
    unsigned short* wgate = (unsigned short*)(ws + OFF_WGATE);
    unsigned short* wup = (unsigned short*)(ws + OFF_WUP);
    unsigned short* wdown = (unsigned short*)(ws + OFF_WDOWN);
    unsigned short* xn1 = (unsigned short*)(ws + OFF_XN1);
    unsigned short* qkvb = (unsigned short*)(ws + OFF_QKVB);
    unsigned short* p2 = (unsigned short*)(ws + OFF_P2);
    unsigned short* p4 = (unsigned short*)(ws + OFF_P4);
    unsigned short* qb = (unsigned short*)(ws + OFF_QB);
    unsigned short* kb = (unsigned short*)(ws + OFF_KB);
    unsigned short* vtb = (unsigned short*)(ws + OFF_VT);
    unsigned short* ctx = (unsigned short*)(ws + OFF_CTX);
    float* x2 = (float*)(ws + OFF_X2);
    unsigned short* xn2 = (unsigned short*)(ws + OFF_XN2);
    unsigned short* g = (unsigned short*)(ws + OFF_G);
    float* outx = (float*)d_out;
    float* outk = outx + (size_t)NTOK * C;

    // merged weight cast + transpose (W[K][N] -> Wt[N][K] bf16)
    transpose_all<<<15360, 256, 0, stream>>>(q_kernel, k_kernel, v_kernel, out_kernel,
                                             gate_kernel, up_kernel, down_kernel,
                                             wqkv, wout, wgate, wup, wdown);

    // attention input norm
    rms_kernel<<<NTOK, 256, 0, stream>>>(x, rms1_scale, xn1);

    // QKV projection -> bf16 [4096][2048]
    gemm128<4><<<dim3(2048 / 128, NTOK / 128), 256, 0, stream>>>(
        xn1, wqkv, qkvb, 2048, 1024, 1024, 1024, 0, 0, 0);

    // RoPE + layout scatter, V transpose
    rope_kernel<<<NTOK, 256, 0, stream>>>(qkvb, qb, kb);
    vtrans_kernel<<<dim3(T / 64, NKV, Bsz), 256, 0, stream>>>(qkvb, vtb);

    // attention
    attn_kernel<<<dim3(T / 64, NH, Bsz), 256, 0, stream>>>(qb, kb, vtb, ctx);

    // out projection, split-K=4 bf16 partials, then fused residual+rms2
    gemm128<4><<<dim3(1024 / 128, NTOK / 128, 4), 256, 0, stream>>>(
        ctx, wout, p2, 1024, 256, 1024, 1024, 256, 256, (size_t)NTOK * 1024);
    reduce_out<<<NTOK, 256, 0, stream>>>(p2, x, rms2_scale, x2, xn2);

    // fused gate+up -> g = silu(gate)*up, bf16 [4096][4096]
    gateup_kernel<<<dim3(HID / 64, NTOK / 128), 256, 0, stream>>>(xn2, wgate, wup, g);

    // down projection, split-K=4 bf16 partials, then fused residual+kurtosis
    gemm128<4><<<dim3(1024 / 128, NTOK / 128, 4), 256, 0, stream>>>(
        g, wdown, p4, 1024, 1024, 4096, 4096, 1024, 1024, (size_t)NTOK * 1024);
    kurt_init<<<1, 1, 0, stream>>>(outk, ksum);
    reduce_down<<<NTOK, 256, 0, stream>>>(p4, x2, outx, outk);

    (void)in_sizes; (void)n_in; (void)out_size; (void)ws_size;
}

// Round 4
// 455.340 us; speedup vs baseline: 1.1522x; 1.1522x over previous
//
#include <hip/hip_runtime.h>
#include <hip/hip_bf16.h>

typedef __attribute__((ext_vector_type(8))) short short8;
typedef __attribute__((ext_vector_type(4))) float f32x4;

#define DEVFN static __device__ __forceinline__

DEVFN float bf2f(unsigned short u) {
    unsigned int i = ((unsigned int)u) << 16;
    float f; __builtin_memcpy(&f, &i, 4); return f;
}
DEVFN unsigned short f2bf(float f) {
    unsigned int i; __builtin_memcpy(&i, &f, 4);
    unsigned int r = i + 0x7fffu + ((i >> 16) & 1u);
    return (unsigned short)(r >> 16);
}

DEVFN void load_lds16(const void* g, void* l) {
    __builtin_amdgcn_global_load_lds(
        (__attribute__((address_space(1))) void*)g,
        (__attribute__((address_space(3))) void*)l, 16, 0, 0);
}

// ---------------- constants ----------------
constexpr int Bsz = 2, T = 2048, C = 1024;
constexpr int NH = 16, NKV = 8, HD = 64;
constexpr int HID = 4096;
constexpr int NTOK = Bsz * T;              // 4096
constexpr size_t MiB = 1024 * 1024;

// workspace offsets (bytes)
constexpr size_t OFF_WQKV = 0;             // bf16 [2048][1024]   4 MiB
constexpr size_t OFF_WOUT = 4 * MiB;       // bf16 [1024][1024]   2 MiB
constexpr size_t OFF_WGATE = 6 * MiB;      // bf16 [4096][1024]   8 MiB
constexpr size_t OFF_WUP = 14 * MiB;       // bf16 [4096][1024]   8 MiB
constexpr size_t OFF_WDOWN = 22 * MiB;     // bf16 [1024][4096]   8 MiB
constexpr size_t OFF_XN1 = 30 * MiB;       // bf16 [4096][1024]   8 MiB
constexpr size_t OFF_QKVB = 38 * MiB;      // bf16 [4096][2048]  16 MiB (dead after rope/vtrans)
constexpr size_t OFF_P2 = 38 * MiB;        // bf16 4x[4096][1024] 32 MiB (out-proj partials; reuses QKVB)
constexpr size_t OFF_P4 = 30 * MiB;        // bf16 4x[4096][1024] 32 MiB (down partials; xn1/p2 dead by then)
constexpr size_t OFF_QB = 70 * MiB;        // bf16 [2][16][2048][64] 8 MiB
constexpr size_t OFF_KB = 78 * MiB;        // bf16 [2][8][2048][64]  4 MiB
constexpr size_t OFF_VT = 82 * MiB;        // bf16 [2][8][64][2048]  4 MiB
constexpr size_t OFF_CTX = 86 * MiB;       // bf16 [4096][1024]   8 MiB
constexpr size_t OFF_X2 = 94 * MiB;        // f32  [4096][1024]  16 MiB
constexpr size_t OFF_XN2 = 110 * MiB;      // bf16 [4096][1024]   8 MiB
constexpr size_t OFF_G = 118 * MiB;        // bf16 [4096][4096]  32 MiB
// total 150 MiB

// ---------------- merged weight cast + transpose: in[K][N] f32 -> out[N][K] bf16 ----------------
__global__ __launch_bounds__(256) void transpose_all(
    const float* __restrict__ qk, const float* __restrict__ kk2,
    const float* __restrict__ vk, const float* __restrict__ ok,
    const float* __restrict__ gk, const float* __restrict__ uk,
    const float* __restrict__ dk,
    unsigned short* __restrict__ wqkv, unsigned short* __restrict__ wout,
    unsigned short* __restrict__ wgate, unsigned short* __restrict__ wup,
    unsigned short* __restrict__ wdown) {
    __shared__ float t[32][33];
    int id = blockIdx.x;
    const float* in; unsigned short* out; int K, N, nx, base;
    if (id < 1024)       { in = qk;  out = wqkv;                        K = 1024; N = 1024; nx = 32;  base = 0; }
    else if (id < 1536)  { in = kk2; out = wqkv + (size_t)1024 * 1024;  K = 1024; N = 512;  nx = 16;  base = 1024; }
    else if (id < 2048)  { in = vk;  out = wqkv + (size_t)1536 * 1024;  K = 1024; N = 512;  nx = 16;  base = 1536; }
    else if (id < 3072)  { in = ok;  out = wout;                        K = 1024; N = 1024; nx = 32;  base = 2048; }
    else if (id < 7168)  { in = gk;  out = wgate;                       K = 1024; N = 4096; nx = 128; base = 3072; }
    else if (id < 11264) { in = uk;  out = wup;                         K = 1024; N = 4096; nx = 128; base = 7168; }
    else                 { in = dk;  out = wdown;                       K = 4096; N = 1024; nx = 32;  base = 11264; }
    int lid = id - base;
    int n0 = (lid % nx) * 32, k0 = (lid / nx) * 32;
    int tx = threadIdx.x & 31, ty = threadIdx.x >> 5;
#pragma unroll
    for (int i = 0; i < 4; i++)
        t[ty + 8 * i][tx] = in[(size_t)(k0 + ty + 8 * i) * N + n0 + tx];
    __syncthreads();
#pragma unroll
    for (int i = 0; i < 4; i++)
        out[(size_t)(n0 + ty + 8 * i) * K + k0 + tx] = f2bf(t[tx][ty + 8 * i]);
}

// ---------------- RMS norm: f32 [rows][1024] -> bf16, *(1+scale) ----------------
__global__ __launch_bounds__(256) void rms_kernel(const float* __restrict__ in,
                                                  const float* __restrict__ scale,
                                                  unsigned short* __restrict__ out) {
    __shared__ float red[4];
    int row = blockIdx.x, tid = threadIdx.x;
    const float4 v = *(const float4*)&in[(size_t)row * 1024 + tid * 4];
    float ss = v.x * v.x + v.y * v.y + v.z * v.z + v.w * v.w;
#pragma unroll
    for (int m = 32; m; m >>= 1) ss += __shfl_xor(ss, m, 64);
    if ((tid & 63) == 0) red[tid >> 6] = ss;
    __syncthreads();
    float tot = red[0] + red[1] + red[2] + red[3];
    float inv = rsqrtf(tot * (1.f / 1024.f) + 1e-6f);
    const float4 sc = *(const float4*)&scale[tid * 4];
    size_t o = (size_t)row * 1024 + tid * 4;
    out[o + 0] = f2bf(v.x * inv * (1.f + sc.x));
    out[o + 1] = f2bf(v.y * inv * (1.f + sc.y));
    out[o + 2] = f2bf(v.z * inv * (1.f + sc.z));
    out[o + 3] = f2bf(v.w * inv * (1.f + sc.w));
}

// ---------------- GEMM: C[M][N](+z) = A[M][K] @ Bt[N][K]^T, bf16 in, fp32 acc ----------------
// r2 staging pattern: lane-contiguous global addresses (4 lanes = one 64B row segment).
// EPI: 0 = fp32 store; 4 = bf16 store. blockIdx.z selects K-slice.
template <int EPI>
__global__ __launch_bounds__(256) void gemm128(const unsigned short* __restrict__ A,
                                               const unsigned short* __restrict__ Bt,
                                               void* __restrict__ Cp,
                                               int N, int K, int lda, int ldb,
                                               size_t zA, size_t zB, size_t zC) {
    __shared__ __align__(16) unsigned short As[128 * 32];
    __shared__ __align__(16) unsigned short Bs[128 * 32];
    A += (size_t)blockIdx.z * zA;
    Bt += (size_t)blockIdx.z * zB;
    const int tid = threadIdx.x;
    const int lane = tid & 63, w = tid >> 6;
    const int quad = lane >> 4, l15 = lane & 15;
    const int wr = w >> 1, wc = w & 1;
    const int m0 = blockIdx.y * 128, n0 = blockIdx.x * 128;

    f32x4 acc[4][4];
#pragma unroll
    for (int i = 0; i < 4; i++)
#pragma unroll
        for (int j = 0; j < 4; j++) acc[i][j] = f32x4{0.f, 0.f, 0.f, 0.f};

    const int stRow = (w << 4) + (lane >> 2);
    const int stCol = (lane & 3) << 3;

    for (int kk = 0; kk < K; kk += 32) {
#pragma unroll
        for (int i = 0; i < 2; i++) {
            load_lds16(A + (size_t)(m0 + (i << 6) + stRow) * lda + kk + stCol,
                       &As[((i << 6) + (w << 4)) * 32]);
            load_lds16(Bt + (size_t)(n0 + (i << 6) + stRow) * ldb + kk + stCol,
                       &Bs[((i << 6) + (w << 4)) * 32]);
        }
        __syncthreads();
        short8 a[4], b[4];
#pragma unroll
        for (int mi = 0; mi < 4; mi++)
            a[mi] = *(const short8*)&As[(wr * 64 + mi * 16 + l15) * 32 + quad * 8];
#pragma unroll
        for (int ni = 0; ni < 4; ni++)
            b[ni] = *(const short8*)&Bs[(wc * 64 + ni * 16 + l15) * 32 + quad * 8];
#pragma unroll
        for (int mi = 0; mi < 4; mi++)
#pragma unroll
            for (int ni = 0; ni < 4; ni++)
                acc[mi][ni] = __builtin_amdgcn_mfma_f32_16x16x32_bf16(a[mi], b[ni], acc[mi][ni], 0, 0, 0);
        __syncthreads();
    }
#pragma unroll
    for (int mi = 0; mi < 4; mi++) {
#pragma unroll
        for (int ni = 0; ni < 4; ni++) {
#pragma unroll
            for (int r = 0; r < 4; r++) {
                int row = m0 + wr * 64 + mi * 16 + quad * 4 + r;
                int col = n0 + wc * 64 + ni * 16 + l15;
                size_t idx = (size_t)blockIdx.z * zC + (size_t)row * N + col;
                float v = acc[mi][ni][r];
                if constexpr (EPI == 0) {
                    ((float*)Cp)[idx] = v;
                } else {
                    ((unsigned short*)Cp)[idx] = f2bf(v);
                }
            }
        }
    }
}

// ---------------- fused gate+up GEMM: 128x128 tile of BOTH gate and up, epilogue silu(g)*u ----------------
__global__ __launch_bounds__(256, 2) void gateup_kernel(const unsigned short* __restrict__ A,
                                                        const unsigned short* __restrict__ Bg,
                                                        const unsigned short* __restrict__ Bu,
                                                        unsigned short* __restrict__ out) {
    __shared__ __align__(16) unsigned short As[128 * 32];
    __shared__ __align__(16) unsigned short Gs[128 * 32];
    __shared__ __align__(16) unsigned short Us[128 * 32];
    const int tid = threadIdx.x;
    const int lane = tid & 63, w = tid >> 6;
    const int quad = lane >> 4, l15 = lane & 15;
    const int wr = w >> 1, wc = w & 1;
    const int m0 = blockIdx.y * 128, n0 = blockIdx.x * 128;

    f32x4 aG[4][4], aU[4][4];
#pragma unroll
    for (int i = 0; i < 4; i++)
#pragma unroll
        for (int j = 0; j < 4; j++) { aG[i][j] = f32x4{0.f, 0.f, 0.f, 0.f}; aU[i][j] = f32x4{0.f, 0.f, 0.f, 0.f}; }

    const int stRow = (w << 4) + (lane >> 2);
    const int stCol = (lane & 3) << 3;

    for (int kk = 0; kk < 1024; kk += 32) {
#pragma unroll
        for (int i = 0; i < 2; i++) {
            load_lds16(A + (size_t)(m0 + (i << 6) + stRow) * 1024 + kk + stCol,
                       &As[((i << 6) + (w << 4)) * 32]);
            load_lds16(Bg + (size_t)(n0 + (i << 6) + stRow) * 1024 + kk + stCol,
                       &Gs[((i << 6) + (w << 4)) * 32]);
            load_lds16(Bu + (size_t)(n0 + (i << 6) + stRow) * 1024 + kk + stCol,
                       &Us[((i << 6) + (w << 4)) * 32]);
        }
        __syncthreads();
        short8 a[4], bg[4], bu[4];
#pragma unroll
        for (int mi = 0; mi < 4; mi++)
            a[mi] = *(const short8*)&As[(wr * 64 + mi * 16 + l15) * 32 + quad * 8];
#pragma unroll
        for (int ni = 0; ni < 4; ni++) {
            bg[ni] = *(const short8*)&Gs[(wc * 64 + ni * 16 + l15) * 32 + quad * 8];
            bu[ni] = *(const short8*)&Us[(wc * 64 + ni * 16 + l15) * 32 + quad * 8];
        }
#pragma unroll
        for (int mi = 0; mi < 4; mi++)
#pragma unroll
            for (int ni = 0; ni < 4; ni++) {
                aG[mi][ni] = __builtin_amdgcn_mfma_f32_16x16x32_bf16(a[mi], bg[ni], aG[mi][ni], 0, 0, 0);
                aU[mi][ni] = __builtin_amdgcn_mfma_f32_16x16x32_bf16(a[mi], bu[ni], aU[mi][ni], 0, 0, 0);
            }
        __syncthreads();
    }
#pragma unroll
    for (int mi = 0; mi < 4; mi++)
#pragma unroll
        for (int ni = 0; ni < 4; ni++)
#pragma unroll
            for (int r = 0; r < 4; r++) {
                int row = m0 + wr * 64 + mi * 16 + quad * 4 + r;
                int col = n0 + wc * 64 + ni * 16 + l15;
                float vg = aG[mi][ni][r], vu = aU[mi][ni][r];
                float s = vg / (1.f + __expf(-vg));
                out[(size_t)row * 4096 + col] = f2bf(s * vu);
            }
}

// ---------------- out-proj reduce: x2 = sum(p[0..3]) + x; xn2 = rms(x2)*(1+scale) ----------------
__global__ __launch_bounds__(256) void reduce_out(const unsigned short* __restrict__ p,
                                                  const float* __restrict__ x,
                                                  const float* __restrict__ scale,
                                                  float* __restrict__ x2,
                                                  unsigned short* __restrict__ xn2) {
    __shared__ float red[4];
    int row = blockIdx.x, tid = threadIdx.x;
    size_t base = (size_t)row * 1024 + tid * 4;
    const size_t Z = (size_t)NTOK * 1024;
    float4 v = *(const float4*)&x[base];
#pragma unroll
    for (int z = 0; z < 4; z++) {
        ushort4 u = *(const ushort4*)&p[base + z * Z];
        v.x += bf2f(u.x); v.y += bf2f(u.y); v.z += bf2f(u.z); v.w += bf2f(u.w);
    }
    *(float4*)&x2[base] = v;
    float ss = v.x * v.x + v.y * v.y + v.z * v.z + v.w * v.w;
#pragma unroll
    for (int m = 32; m; m >>= 1) ss += __shfl_xor(ss, m, 64);
    if ((tid & 63) == 0) red[tid >> 6] = ss;
    __syncthreads();
    float tot = red[0] + red[1] + red[2] + red[3];
    float inv = rsqrtf(tot * (1.f / 1024.f) + 1e-6f);
    const float4 sc = *(const float4*)&scale[tid * 4];
    xn2[base + 0] = f2bf(v.x * inv * (1.f + sc.x));
    xn2[base + 1] = f2bf(v.y * inv * (1.f + sc.y));
    xn2[base + 2] = f2bf(v.z * inv * (1.f + sc.z));
    xn2[base + 3] = f2bf(v.w * inv * (1.f + sc.w));
}

// ---------------- down reduce: out = sum(p[0..3]) + x2, fused kurtosis ----------------
__global__ __launch_bounds__(256) void reduce_down(const unsigned short* __restrict__ p,
                                                   const float* __restrict__ x2,
                                                   float* __restrict__ outx,
                                                   float* __restrict__ outk) {
    __shared__ float red[4], r2[4], r4[4];
    int row = blockIdx.x, tid = threadIdx.x;
    size_t base = (size_t)row * 1024 + tid * 4;
    const size_t Z = (size_t)NTOK * 1024;
    float4 v = *(const float4*)&x2[base];
#pragma unroll
    for (int z = 0; z < 4; z++) {
        ushort4 u = *(const ushort4*)&p[base + z * Z];
        v.x += bf2f(u.x); v.y += bf2f(u.y); v.z += bf2f(u.z); v.w += bf2f(u.w);
    }
    *(float4*)&outx[base] = v;
    float s = v.x + v.y + v.z + v.w;
#pragma unroll
    for (int m = 32; m; m >>= 1) s += __shfl_xor(s, m, 64);
    if ((tid & 63) == 0) red[tid >> 6] = s;
    __syncthreads();
    float mean = (red[0] + red[1] + red[2] + red[3]) * (1.f / 1024.f);
    float cx = v.x - mean, cy = v.y - mean, cz = v.z - mean, cw = v.w - mean;
    float x2v = cx * cx, y2 = cy * cy, z2 = cz * cz, w2 = cw * cw;
    float c2 = x2v + y2 + z2 + w2;
    float c4 = x2v * x2v + y2 * y2 + z2 * z2 + w2 * w2;
#pragma unroll
    for (int m = 32; m; m >>= 1) {
        c2 += __shfl_xor(c2, m, 64);
        c4 += __shfl_xor(c4, m, 64);
    }
    if ((tid & 63) == 0) { r2[tid >> 6] = c2; r4[tid >> 6] = c4; }
    __syncthreads();
    if (tid == 0) {
        float m2 = (r2[0] + r2[1] + r2[2] + r2[3]) * (1.f / 1024.f);
        float m4 = (r4[0] + r4[1] + r4[2] + r4[3]) * (1.f / 1024.f);
        float kurt = m4 / (m2 * m2 + 1e-6f) - 3.f;
        if (kurt > 0.f) atomicAdd(outk, kurt);
    }
}

// ---------------- RoPE scatter: qkvb bf16 [tok][2048] -> qb/kb bf16 head-major ----------------
__global__ __launch_bounds__(256) void rope_kernel(const unsigned short* __restrict__ qkvb,
                                                   unsigned short* __restrict__ qb,
                                                   unsigned short* __restrict__ kb) {
    __shared__ float sv[32], cv[32];
    int tok = blockIdx.x;
    int b = tok >> 11, t = tok & 2047;
    int tid = threadIdx.x;
    if (tid < 32) {
        float fr = (float)tid * (1.f / 32.f);
        float freq = powf(1e6f, -fr);
        float a = (float)t * freq;
        sv[tid] = sinf(a);
        cv[tid] = cosf(a);
    }
    __syncthreads();
    const unsigned short* rowp = qkvb + (size_t)tok * 2048;
#pragma unroll
    for (int e = tid; e < 1536; e += 256) {
        int u = e >> 6, d = e & 63;
        int col = (u < 16) ? (u * 64 + d) : (1024 + (u - 16) * 64 + d);
        int pcol = (d < 32) ? col + 32 : col - 32;
        float sgn = (d < 32) ? -1.f : 1.f;
        float o = bf2f(rowp[col]) * cv[d & 31] + sgn * bf2f(rowp[pcol]) * sv[d & 31];
        if (u < 16)
            qb[((size_t)(b * 16 + u) * 2048 + t) * 64 + d] = f2bf(o);
        else
            kb[((size_t)(b * 8 + (u - 16)) * 2048 + t) * 64 + d] = f2bf(o);
    }
}

// ---------------- V transpose: qkvb v-cols -> vt bf16 [b][h][64 d][2048 t] ----------------
__global__ __launch_bounds__(256) void vtrans_kernel(const unsigned short* __restrict__ qkvb,
                                                     unsigned short* __restrict__ vt) {
    __shared__ unsigned short tile[64][68];
    int t0 = blockIdx.x * 64, h = blockIdx.y, b = blockIdx.z;
    int tid = threadIdx.x;
    int d = tid & 63, tr = tid >> 6;
#pragma unroll
    for (int i = 0; i < 16; i++) {
        int t = tr + i * 4;
        tile[t][d] = qkvb[(size_t)(b * 2048 + t0 + t) * 2048 + 1536 + h * 64 + d];
    }
    __syncthreads();
    int tt = tid & 63, dr = tid >> 6;
#pragma unroll
    for (int i = 0; i < 16; i++) {
        int dd = dr + i * 4;
        vt[((size_t)(b * 8 + h) * 64 + dd) * 2048 + t0 + tt] = tile[tt][dd];
    }
}

// ---------------- flash attention, sliding window, soft cap ----------------
__global__ __launch_bounds__(256) void attn_kernel(const unsigned short* __restrict__ qb,
                                                   const unsigned short* __restrict__ kb,
                                                   const unsigned short* __restrict__ vt,
                                                   unsigned short* __restrict__ ctx) {
    __shared__ __align__(16) unsigned short P[4][16 * 32];
    const int tid = threadIdx.x, lane = tid & 63, w = tid >> 6;
    const int quad = lane >> 4, l15 = lane & 15;
    const int qt = blockIdx.x, H = blockIdx.y, b = blockIdx.z;
    const int hkv = H & 7;
    const int qw = qt * 64 + w * 16;

    const unsigned short* qbase = qb + ((size_t)(b * 16 + H) * 2048 + qw) * 64;
    short8 aq0 = *(const short8*)(qbase + (size_t)l15 * 64 + quad * 8);
    short8 aq1 = *(const short8*)(qbase + (size_t)l15 * 64 + 32 + quad * 8);

    const unsigned short* kbase = kb + (size_t)(b * 8 + hkv) * 2048 * 64;
    const unsigned short* vbase = vt + (size_t)(b * 8 + hkv) * 64 * 2048;

    f32x4 O[4];
#pragma unroll
    for (int i = 0; i < 4; i++) O[i] = f32x4{0.f, 0.f, 0.f, 0.f};
    float mrow[4], lrow[4];
#pragma unroll
    for (int r = 0; r < 4; r++) { mrow[r] = -1e30f; lrow[r] = 0.f; }

    int kstart = qw - 511;
    if (kstart < 0) kstart = 0;
    kstart &= ~31;
    unsigned short* Pw = P[w];

    for (int k0 = kstart; k0 <= qw + 15; k0 += 32) {
        f32x4 S[2];
#pragma unroll
        for (int c = 0; c < 2; c++) {
            const unsigned short* kp = kbase + (size_t)(k0 + c * 16 + l15) * 64 + quad * 8;
            short8 kf0 = *(const short8*)kp;
            short8 kf1 = *(const short8*)(kp + 32);
            f32x4 s = __builtin_amdgcn_mfma_f32_16x16x32_bf16(aq0, kf0, f32x4{0.f, 0.f, 0.f, 0.f}, 0, 0, 0);
            s = __builtin_amdgcn_mfma_f32_16x16x32_bf16(aq1, kf1, s, 0, 0, 0);
            S[c] = s;
        }
        float y[2][4];
#pragma unroll
        for (int c = 0; c < 2; c++)
#pragma unroll
            for (int r = 0; r < 4; r++) {
                int i = qw + quad * 4 + r;
                int j = k0 + c * 16 + l15;
                float x = S[c][r] * 0.125f;
                float tt = x * 0.02f;
                tt = fminf(8.f, fmaxf(-8.f, tt));
                float e = __expf(2.f * tt);
                float yv = 50.f * (e - 1.f) / (e + 1.f);
                y[c][r] = (j <= i && (i - j) < 512) ? yv : -__builtin_inff();
            }
        float p[2][4], alpha[4];
#pragma unroll
        for (int r = 0; r < 4; r++) {
            float v = fmaxf(y[0][r], y[1][r]);
#pragma unroll
            for (int mm = 8; mm; mm >>= 1) v = fmaxf(v, __shfl_xor(v, mm, 16));
            float mnew = fmaxf(mrow[r], v);
            alpha[r] = __expf(mrow[r] - mnew);
            float p0 = __expf(y[0][r] - mnew);
            float p1 = __expf(y[1][r] - mnew);
            p[0][r] = p0; p[1][r] = p1;
            float rs = p0 + p1;
#pragma unroll
            for (int mm = 8; mm; mm >>= 1) rs += __shfl_xor(rs, mm, 16);
            lrow[r] = lrow[r] * alpha[r] + rs;
            mrow[r] = mnew;
        }
#pragma unroll
        for (int c = 0; c < 2; c++)
#pragma unroll
            for (int r = 0; r < 4; r++)
                Pw[(quad * 4 + r) * 32 + c * 16 + l15] = f2bf(p[c][r]);
        asm volatile("s_waitcnt lgkmcnt(0)" ::: "memory");
        short8 pf = *(const short8*)&Pw[l15 * 32 + quad * 8];
#pragma unroll
        for (int ni = 0; ni < 4; ni++) {
            short8 vf = *(const short8*)(vbase + (size_t)(ni * 16 + l15) * 2048 + k0 + quad * 8);
            f32x4 o = O[ni];
#pragma unroll
            for (int r = 0; r < 4; r++) o[r] *= alpha[r];
            O[ni] = __builtin_amdgcn_mfma_f32_16x16x32_bf16(pf, vf, o, 0, 0, 0);
        }
        asm volatile("s_waitcnt lgkmcnt(0)" ::: "memory");
    }
#pragma unroll
    for (int r = 0; r < 4; r++) {
        float inv = 1.f / lrow[r];
        int i = qw + quad * 4 + r;
        size_t tok = (size_t)b * 2048 + i;
#pragma unroll
        for (int ni = 0; ni < 4; ni++)
            ctx[tok * 1024 + H * 64 + ni * 16 + l15] = f2bf(O[ni][r] * inv);
    }
}

// ---------------- kurtosis init ----------------
__global__ void kurt_init(float* dst, const float* ksum) { dst[0] = ksum[0]; }

// ---------------- launch ----------------
extern "C" void kernel_launch(void* const* d_in, const int* in_sizes, int n_in,
                              void* d_out, int out_size, void* d_ws, size_t ws_size,
                              hipStream_t stream) {
    const float* x = (const float*)d_in[0];
    const float* ksum = (const float*)d_in[1];
    const float* rms1_scale = (const float*)d_in[2];
    const float* q_kernel = (const float*)d_in[3];
    const float* k_kernel = (const float*)d_in[4];
    const float* v_kernel = (const float*)d_in[5];
    const float* out_kernel = (const float*)d_in[6];
    const float* rms2_scale = (const float*)d_in[7];
    const float* gate_kernel = (const float*)d_in[8];
    const float* up_kernel = (const float*)d_in[9];
    const float* down_kernel = (const float*)d_in[10];

    char* ws = (char*)d_ws;
    unsigned short* wqkv = (unsigned short*)(ws + OFF_WQKV);
    unsigned short* wout = (unsigned short*)(ws + OFF_WOUT);
    unsigned short* wgate = (unsigned short*)(ws + OFF_WGATE);
    unsigned short* wup = (unsigned short*)(ws + OFF_WUP);
    unsigned short* wdown = (unsigned short*)(ws + OFF_WDOWN);
    unsigned short* xn1 = (unsigned short*)(ws + OFF_XN1);
    unsigned short* qkvb = (unsigned short*)(ws + OFF_QKVB);
    unsigned short* p2 = (unsigned short*)(ws + OFF_P2);
    unsigned short* p4 = (unsigned short*)(ws + OFF_P4);
    unsigned short* qb = (unsigned short*)(ws + OFF_QB);
    unsigned short* kb = (unsigned short*)(ws + OFF_KB);
    unsigned short* vtb = (unsigned short*)(ws + OFF_VT);
    unsigned short* ctx = (unsigned short*)(ws + OFF_CTX);
    float* x2 = (float*)(ws + OFF_X2);
    unsigned short* xn2 = (unsigned short*)(ws + OFF_XN2);
    unsigned short* g = (unsigned short*)(ws + OFF_G);
    float* outx = (float*)d_out;
    float* outk = outx + (size_t)NTOK * C;

    // merged weight cast + transpose (W[K][N] -> Wt[N][K] bf16)
    transpose_all<<<15360, 256, 0, stream>>>(q_kernel, k_kernel, v_kernel, out_kernel,
                                             gate_kernel, up_kernel, down_kernel,
                                             wqkv, wout, wgate, wup, wdown);

    // attention input norm
    rms_kernel<<<NTOK, 256, 0, stream>>>(x, rms1_scale, xn1);

    // QKV projection -> bf16 [4096][2048]
    gemm128<4><<<dim3(2048 / 128, NTOK / 128), 256, 0, stream>>>(
        xn1, wqkv, qkvb, 2048, 1024, 1024, 1024, 0, 0, 0);

    // RoPE + layout scatter, V transpose
    rope_kernel<<<NTOK, 256, 0, stream>>>(qkvb, qb, kb);
    vtrans_kernel<<<dim3(T / 64, NKV, Bsz), 256, 0, stream>>>(qkvb, vtb);

    // attention
    attn_kernel<<<dim3(T / 64, NH, Bsz), 256, 0, stream>>>(qb, kb, vtb, ctx);

    // out projection, split-K=4 bf16 partials, then fused residual+rms2
    gemm128<4><<<dim3(1024 / 128, NTOK / 128, 4), 256, 0, stream>>>(
        ctx, wout, p2, 1024, 256, 1024, 1024, 256, 256, (size_t)NTOK * 1024);
    reduce_out<<<NTOK, 256, 0, stream>>>(p2, x, rms2_scale, x2, xn2);

    // fused gate+up 128x128 -> g = silu(gate)*up, bf16 [4096][4096]
    gateup_kernel<<<dim3(HID / 128, NTOK / 128), 256, 0, stream>>>(xn2, wgate, wup, g);

    // down projection, split-K=4 bf16 partials, then fused residual+kurtosis
    gemm128<4><<<dim3(1024 / 128, NTOK / 128, 4), 256, 0, stream>>>(
        g, wdown, p4, 1024, 1024, 4096, 4096, 1024, 1024, (size_t)NTOK * 1024);
    kurt_init<<<1, 1, 0, stream>>>(outk, ksum);
    reduce_down<<<NTOK, 256, 0, stream>>>(p4, x2, outx, outk);

    (void)in_sizes; (void)n_in; (void)out_size; (void)ws_size;
}

// Round 5
// 450.131 us; speedup vs baseline: 1.1655x; 1.0116x over previous
//
#include <hip/hip_runtime.h>
#include <hip/hip_bf16.h>

typedef __attribute__((ext_vector_type(8))) short short8;
typedef __attribute__((ext_vector_type(4))) float f32x4;

#define DEVFN static __device__ __forceinline__

DEVFN float bf2f(unsigned short u) {
    unsigned int i = ((unsigned int)u) << 16;
    float f; __builtin_memcpy(&f, &i, 4); return f;
}
DEVFN unsigned short f2bf(float f) {
    unsigned int i; __builtin_memcpy(&i, &f, 4);
    unsigned int r = i + 0x7fffu + ((i >> 16) & 1u);
    return (unsigned short)(r >> 16);
}

DEVFN void load_lds16(const void* g, void* l) {
    __builtin_amdgcn_global_load_lds(
        (__attribute__((address_space(1))) void*)g,
        (__attribute__((address_space(3))) void*)l, 16, 0, 0);
}

// ---------------- constants ----------------
constexpr int Bsz = 2, T = 2048, C = 1024;
constexpr int NH = 16, NKV = 8, HD = 64;
constexpr int HID = 4096;
constexpr int NTOK = Bsz * T;              // 4096
constexpr size_t MiB = 1024 * 1024;

// workspace offsets (bytes)
constexpr size_t OFF_WQKV = 0;             // bf16 [2048][1024]   4 MiB
constexpr size_t OFF_WOUT = 4 * MiB;       // bf16 [1024][1024]   2 MiB
constexpr size_t OFF_WGATE = 6 * MiB;      // bf16 [4096][1024]   8 MiB
constexpr size_t OFF_WUP = 14 * MiB;       // bf16 [4096][1024]   8 MiB
constexpr size_t OFF_WDOWN = 22 * MiB;     // bf16 [1024][4096]   8 MiB
constexpr size_t OFF_XN1 = 30 * MiB;       // bf16 [4096][1024]   8 MiB
constexpr size_t OFF_QKVP = 38 * MiB;      // bf16 2x[4096][2048] 32 MiB (qkv split-K partials; dead after ropevt)
constexpr size_t OFF_P2 = 38 * MiB;        // bf16 4x[4096][1024] 32 MiB (out-proj partials; reuses QKVP)
constexpr size_t OFF_P4 = 30 * MiB;        // bf16 4x[4096][1024] 32 MiB (down partials; xn1/p2 dead by then)
constexpr size_t OFF_QB = 70 * MiB;        // bf16 [2][16][2048][64] 8 MiB
constexpr size_t OFF_KB = 78 * MiB;        // bf16 [2][8][2048][64]  4 MiB
constexpr size_t OFF_VT = 82 * MiB;        // bf16 [2][8][64][2048]  4 MiB
constexpr size_t OFF_CTX = 86 * MiB;       // bf16 [4096][1024]   8 MiB
constexpr size_t OFF_X2 = 94 * MiB;        // f32  [4096][1024]  16 MiB
constexpr size_t OFF_XN2 = 110 * MiB;      // bf16 [4096][1024]   8 MiB
constexpr size_t OFF_G = 118 * MiB;        // bf16 [4096][4096]  32 MiB
// total 150 MiB

// ---------------- prep: weight cast+transpose (7 mats) + rms1, one launch ----------------
// blocks [0,15360): transpose 32x32 tiles; [15360,19456): rms rows
__global__ __launch_bounds__(256) void prep_kernel(
    const float* __restrict__ qk, const float* __restrict__ kk2,
    const float* __restrict__ vk, const float* __restrict__ ok,
    const float* __restrict__ gk, const float* __restrict__ uk,
    const float* __restrict__ dk,
    unsigned short* __restrict__ wqkv, unsigned short* __restrict__ wout,
    unsigned short* __restrict__ wgate, unsigned short* __restrict__ wup,
    unsigned short* __restrict__ wdown,
    const float* __restrict__ x, const float* __restrict__ rms1_scale,
    unsigned short* __restrict__ xn1) {
    __shared__ float t[32][33];
    __shared__ float red[4];
    int id = blockIdx.x;
    int tid = threadIdx.x;
    if (id >= 15360) {
        // rms1 for row id-15360
        int row = id - 15360;
        const float4 v = *(const float4*)&x[(size_t)row * 1024 + tid * 4];
        float ss = v.x * v.x + v.y * v.y + v.z * v.z + v.w * v.w;
#pragma unroll
        for (int m = 32; m; m >>= 1) ss += __shfl_xor(ss, m, 64);
        if ((tid & 63) == 0) red[tid >> 6] = ss;
        __syncthreads();
        float tot = red[0] + red[1] + red[2] + red[3];
        float inv = rsqrtf(tot * (1.f / 1024.f) + 1e-6f);
        const float4 sc = *(const float4*)&rms1_scale[tid * 4];
        size_t o = (size_t)row * 1024 + tid * 4;
        xn1[o + 0] = f2bf(v.x * inv * (1.f + sc.x));
        xn1[o + 1] = f2bf(v.y * inv * (1.f + sc.y));
        xn1[o + 2] = f2bf(v.z * inv * (1.f + sc.z));
        xn1[o + 3] = f2bf(v.w * inv * (1.f + sc.w));
        return;
    }
    const float* in; unsigned short* out; int K, N, nx, base;
    if (id < 1024)       { in = qk;  out = wqkv;                        K = 1024; N = 1024; nx = 32;  base = 0; }
    else if (id < 1536)  { in = kk2; out = wqkv + (size_t)1024 * 1024;  K = 1024; N = 512;  nx = 16;  base = 1024; }
    else if (id < 2048)  { in = vk;  out = wqkv + (size_t)1536 * 1024;  K = 1024; N = 512;  nx = 16;  base = 1536; }
    else if (id < 3072)  { in = ok;  out = wout;                        K = 1024; N = 1024; nx = 32;  base = 2048; }
    else if (id < 7168)  { in = gk;  out = wgate;                       K = 1024; N = 4096; nx = 128; base = 3072; }
    else if (id < 11264) { in = uk;  out = wup;                         K = 1024; N = 4096; nx = 128; base = 7168; }
    else                 { in = dk;  out = wdown;                       K = 4096; N = 1024; nx = 32;  base = 11264; }
    int lid = id - base;
    int n0 = (lid % nx) * 32, k0 = (lid / nx) * 32;
    int tx = tid & 31, ty = tid >> 5;
#pragma unroll
    for (int i = 0; i < 4; i++)
        t[ty + 8 * i][tx] = in[(size_t)(k0 + ty + 8 * i) * N + n0 + tx];
    __syncthreads();
#pragma unroll
    for (int i = 0; i < 4; i++)
        out[(size_t)(n0 + ty + 8 * i) * K + k0 + tx] = f2bf(t[tx][ty + 8 * i]);
}

// ---------------- GEMM: C[M][N](+z) = A[M][K] @ Bt[N][K]^T, bf16 in, fp32 acc ----------------
// r2 staging: lane-contiguous global addresses (4 lanes = one 64B row segment).
// EPI: 0 = fp32 store; 4 = bf16 store. blockIdx.z selects K-slice.
template <int EPI>
__global__ __launch_bounds__(256) void gemm128(const unsigned short* __restrict__ A,
                                               const unsigned short* __restrict__ Bt,
                                               void* __restrict__ Cp,
                                               int N, int K, int lda, int ldb,
                                               size_t zA, size_t zB, size_t zC) {
    __shared__ __align__(16) unsigned short As[128 * 32];
    __shared__ __align__(16) unsigned short Bs[128 * 32];
    A += (size_t)blockIdx.z * zA;
    Bt += (size_t)blockIdx.z * zB;
    const int tid = threadIdx.x;
    const int lane = tid & 63, w = tid >> 6;
    const int quad = lane >> 4, l15 = lane & 15;
    const int wr = w >> 1, wc = w & 1;
    const int m0 = blockIdx.y * 128, n0 = blockIdx.x * 128;

    f32x4 acc[4][4];
#pragma unroll
    for (int i = 0; i < 4; i++)
#pragma unroll
        for (int j = 0; j < 4; j++) acc[i][j] = f32x4{0.f, 0.f, 0.f, 0.f};

    const int stRow = (w << 4) + (lane >> 2);
    const int stCol = (lane & 3) << 3;

    for (int kk = 0; kk < K; kk += 32) {
#pragma unroll
        for (int i = 0; i < 2; i++) {
            load_lds16(A + (size_t)(m0 + (i << 6) + stRow) * lda + kk + stCol,
                       &As[((i << 6) + (w << 4)) * 32]);
            load_lds16(Bt + (size_t)(n0 + (i << 6) + stRow) * ldb + kk + stCol,
                       &Bs[((i << 6) + (w << 4)) * 32]);
        }
        __syncthreads();
        short8 a[4], b[4];
#pragma unroll
        for (int mi = 0; mi < 4; mi++)
            a[mi] = *(const short8*)&As[(wr * 64 + mi * 16 + l15) * 32 + quad * 8];
#pragma unroll
        for (int ni = 0; ni < 4; ni++)
            b[ni] = *(const short8*)&Bs[(wc * 64 + ni * 16 + l15) * 32 + quad * 8];
#pragma unroll
        for (int mi = 0; mi < 4; mi++)
#pragma unroll
            for (int ni = 0; ni < 4; ni++)
                acc[mi][ni] = __builtin_amdgcn_mfma_f32_16x16x32_bf16(a[mi], b[ni], acc[mi][ni], 0, 0, 0);
        __syncthreads();
    }
#pragma unroll
    for (int mi = 0; mi < 4; mi++) {
#pragma unroll
        for (int ni = 0; ni < 4; ni++) {
#pragma unroll
            for (int r = 0; r < 4; r++) {
                int row = m0 + wr * 64 + mi * 16 + quad * 4 + r;
                int col = n0 + wc * 64 + ni * 16 + l15;
                size_t idx = (size_t)blockIdx.z * zC + (size_t)row * N + col;
                float v = acc[mi][ni][r];
                if constexpr (EPI == 0) {
                    ((float*)Cp)[idx] = v;
                } else {
                    ((unsigned short*)Cp)[idx] = f2bf(v);
                }
            }
        }
    }
}

// ---------------- fused gate+up GEMM: 128x64 tile of BOTH gate and up, epilogue silu(g)*u ----------------
__global__ __launch_bounds__(256) void gateup_kernel(const unsigned short* __restrict__ A,
                                                     const unsigned short* __restrict__ Bg,
                                                     const unsigned short* __restrict__ Bu,
                                                     unsigned short* __restrict__ out) {
    __shared__ __align__(16) unsigned short As[128 * 32];
    __shared__ __align__(16) unsigned short Gs[64 * 32];
    __shared__ __align__(16) unsigned short Us[64 * 32];
    const int tid = threadIdx.x;
    const int lane = tid & 63, w = tid >> 6;
    const int quad = lane >> 4, l15 = lane & 15;
    const int wr = w >> 1, wc = w & 1;
    const int m0 = blockIdx.y * 128, n0 = blockIdx.x * 64;

    f32x4 aG[4][2], aU[4][2];
#pragma unroll
    for (int i = 0; i < 4; i++)
#pragma unroll
        for (int j = 0; j < 2; j++) { aG[i][j] = f32x4{0.f, 0.f, 0.f, 0.f}; aU[i][j] = f32x4{0.f, 0.f, 0.f, 0.f}; }

    const int stRow = (w << 4) + (lane >> 2);
    const int stCol = (lane & 3) << 3;

    for (int kk = 0; kk < 1024; kk += 32) {
#pragma unroll
        for (int i = 0; i < 2; i++)
            load_lds16(A + (size_t)(m0 + (i << 6) + stRow) * 1024 + kk + stCol,
                       &As[((i << 6) + (w << 4)) * 32]);
        load_lds16(Bg + (size_t)(n0 + stRow) * 1024 + kk + stCol, &Gs[(w << 4) * 32]);
        load_lds16(Bu + (size_t)(n0 + stRow) * 1024 + kk + stCol, &Us[(w << 4) * 32]);
        __syncthreads();
        short8 a[4], bg[2], bu[2];
#pragma unroll
        for (int mi = 0; mi < 4; mi++)
            a[mi] = *(const short8*)&As[(wr * 64 + mi * 16 + l15) * 32 + quad * 8];
#pragma unroll
        for (int ni = 0; ni < 2; ni++) {
            bg[ni] = *(const short8*)&Gs[(wc * 32 + ni * 16 + l15) * 32 + quad * 8];
            bu[ni] = *(const short8*)&Us[(wc * 32 + ni * 16 + l15) * 32 + quad * 8];
        }
#pragma unroll
        for (int mi = 0; mi < 4; mi++)
#pragma unroll
            for (int ni = 0; ni < 2; ni++) {
                aG[mi][ni] = __builtin_amdgcn_mfma_f32_16x16x32_bf16(a[mi], bg[ni], aG[mi][ni], 0, 0, 0);
                aU[mi][ni] = __builtin_amdgcn_mfma_f32_16x16x32_bf16(a[mi], bu[ni], aU[mi][ni], 0, 0, 0);
            }
        __syncthreads();
    }
#pragma unroll
    for (int mi = 0; mi < 4; mi++)
#pragma unroll
        for (int ni = 0; ni < 2; ni++)
#pragma unroll
            for (int r = 0; r < 4; r++) {
                int row = m0 + wr * 64 + mi * 16 + quad * 4 + r;
                int col = n0 + wc * 32 + ni * 16 + l15;
                float vg = aG[mi][ni][r], vu = aU[mi][ni][r];
                float s = vg / (1.f + __expf(-vg));
                out[(size_t)row * 4096 + col] = f2bf(s * vu);
            }
}

// ---------------- out-proj reduce: x2 = sum(p[0..3]) + x; xn2 = rms(x2)*(1+scale); init outk ----------------
__global__ __launch_bounds__(256) void reduce_out(const unsigned short* __restrict__ p,
                                                  const float* __restrict__ x,
                                                  const float* __restrict__ scale,
                                                  float* __restrict__ x2,
                                                  unsigned short* __restrict__ xn2,
                                                  const float* __restrict__ ksum,
                                                  float* __restrict__ outk) {
    __shared__ float red[4];
    int row = blockIdx.x, tid = threadIdx.x;
    if (row == 0 && tid == 0) outk[0] = ksum[0];
    size_t base = (size_t)row * 1024 + tid * 4;
    const size_t Z = (size_t)NTOK * 1024;
    float4 v = *(const float4*)&x[base];
#pragma unroll
    for (int z = 0; z < 4; z++) {
        ushort4 u = *(const ushort4*)&p[base + z * Z];
        v.x += bf2f(u.x); v.y += bf2f(u.y); v.z += bf2f(u.z); v.w += bf2f(u.w);
    }
    *(float4*)&x2[base] = v;
    float ss = v.x * v.x + v.y * v.y + v.z * v.z + v.w * v.w;
#pragma unroll
    for (int m = 32; m; m >>= 1) ss += __shfl_xor(ss, m, 64);
    if ((tid & 63) == 0) red[tid >> 6] = ss;
    __syncthreads();
    float tot = red[0] + red[1] + red[2] + red[3];
    float inv = rsqrtf(tot * (1.f / 1024.f) + 1e-6f);
    const float4 sc = *(const float4*)&scale[tid * 4];
    xn2[base + 0] = f2bf(v.x * inv * (1.f + sc.x));
    xn2[base + 1] = f2bf(v.y * inv * (1.f + sc.y));
    xn2[base + 2] = f2bf(v.z * inv * (1.f + sc.z));
    xn2[base + 3] = f2bf(v.w * inv * (1.f + sc.w));
}

// ---------------- down reduce: out = sum(p[0..3]) + x2, fused kurtosis ----------------
__global__ __launch_bounds__(256) void reduce_down(const unsigned short* __restrict__ p,
                                                   const float* __restrict__ x2,
                                                   float* __restrict__ outx,
                                                   float* __restrict__ outk) {
    __shared__ float red[4], r2[4], r4[4];
    int row = blockIdx.x, tid = threadIdx.x;
    size_t base = (size_t)row * 1024 + tid * 4;
    const size_t Z = (size_t)NTOK * 1024;
    float4 v = *(const float4*)&x2[base];
#pragma unroll
    for (int z = 0; z < 4; z++) {
        ushort4 u = *(const ushort4*)&p[base + z * Z];
        v.x += bf2f(u.x); v.y += bf2f(u.y); v.z += bf2f(u.z); v.w += bf2f(u.w);
    }
    *(float4*)&outx[base] = v;
    float s = v.x + v.y + v.z + v.w;
#pragma unroll
    for (int m = 32; m; m >>= 1) s += __shfl_xor(s, m, 64);
    if ((tid & 63) == 0) red[tid >> 6] = s;
    __syncthreads();
    float mean = (red[0] + red[1] + red[2] + red[3]) * (1.f / 1024.f);
    float cx = v.x - mean, cy = v.y - mean, cz = v.z - mean, cw = v.w - mean;
    float x2v = cx * cx, y2 = cy * cy, z2 = cz * cz, w2 = cw * cw;
    float c2 = x2v + y2 + z2 + w2;
    float c4 = x2v * x2v + y2 * y2 + z2 * z2 + w2 * w2;
#pragma unroll
    for (int m = 32; m; m >>= 1) {
        c2 += __shfl_xor(c2, m, 64);
        c4 += __shfl_xor(c4, m, 64);
    }
    if ((tid & 63) == 0) { r2[tid >> 6] = c2; r4[tid >> 6] = c4; }
    __syncthreads();
    if (tid == 0) {
        float m2 = (r2[0] + r2[1] + r2[2] + r2[3]) * (1.f / 1024.f);
        float m4 = (r4[0] + r4[1] + r4[2] + r4[3]) * (1.f / 1024.f);
        float kurt = m4 / (m2 * m2 + 1e-6f) - 3.f;
        if (kurt > 0.f) atomicAdd(outk, kurt);
    }
}

// ---------------- ropevt: reduce qkv split-K partials + RoPE scatter + V transpose ----------------
// blocks [0,4096): rope for token id; [4096,4608): V transpose tiles
__global__ __launch_bounds__(256) void ropevt_kernel(const unsigned short* __restrict__ qkvp,
                                                     unsigned short* __restrict__ qb,
                                                     unsigned short* __restrict__ kb,
                                                     unsigned short* __restrict__ vt) {
    __shared__ float sv[32], cv[32];
    __shared__ unsigned short tile[64][68];
    const size_t Z = (size_t)NTOK * 2048;
    int id = blockIdx.x;
    int tid = threadIdx.x;
    if (id < NTOK) {
        int tok = id;
        int b = tok >> 11, t = tok & 2047;
        if (tid < 32) {
            float fr = (float)tid * (1.f / 32.f);
            float freq = powf(1e6f, -fr);
            float a = (float)t * freq;
            sv[tid] = sinf(a);
            cv[tid] = cosf(a);
        }
        __syncthreads();
        const unsigned short* r0 = qkvp + (size_t)tok * 2048;
        const unsigned short* r1 = r0 + Z;
#pragma unroll
        for (int e = tid; e < 1536; e += 256) {
            int u = e >> 6, d = e & 63;
            int col = (u < 16) ? (u * 64 + d) : (1024 + (u - 16) * 64 + d);
            int pcol = (d < 32) ? col + 32 : col - 32;
            float sgn = (d < 32) ? -1.f : 1.f;
            float vc = bf2f(r0[col]) + bf2f(r1[col]);
            float vp = bf2f(r0[pcol]) + bf2f(r1[pcol]);
            float o = vc * cv[d & 31] + sgn * vp * sv[d & 31];
            if (u < 16)
                qb[((size_t)(b * 16 + u) * 2048 + t) * 64 + d] = f2bf(o);
            else
                kb[((size_t)(b * 8 + (u - 16)) * 2048 + t) * 64 + d] = f2bf(o);
        }
    } else {
        int lid = id - NTOK;                    // 0..511
        int b = lid >> 8, h = (lid >> 5) & 7, t0 = (lid & 31) * 64;
        int d = tid & 63, tr = tid >> 6;
#pragma unroll
        for (int i = 0; i < 16; i++) {
            int t = tr + i * 4;
            size_t gi = (size_t)(b * 2048 + t0 + t) * 2048 + 1536 + h * 64 + d;
            tile[t][d] = f2bf(bf2f(qkvp[gi]) + bf2f(qkvp[gi + Z]));
        }
        __syncthreads();
        int tt = tid & 63, dr = tid >> 6;
#pragma unroll
        for (int i = 0; i < 16; i++) {
            int dd = dr + i * 4;
            vt[((size_t)(b * 8 + h) * 64 + dd) * 2048 + t0 + tt] = tile[tt][dd];
        }
    }
}

// ---------------- flash attention, sliding window, soft cap; fixed-m softmax (|y|<=50) ----------------
__global__ __launch_bounds__(256) void attn_kernel(const unsigned short* __restrict__ qb,
                                                   const unsigned short* __restrict__ kb,
                                                   const unsigned short* __restrict__ vt,
                                                   unsigned short* __restrict__ ctx) {
    __shared__ __align__(16) unsigned short P[4][16 * 32];
    const int tid = threadIdx.x, lane = tid & 63, w = tid >> 6;
    const int quad = lane >> 4, l15 = lane & 15;
    const int qt = blockIdx.x, H = blockIdx.y, b = blockIdx.z;
    const int hkv = H & 7;
    const int qw = qt * 64 + w * 16;

    const unsigned short* qbase = qb + ((size_t)(b * 16 + H) * 2048 + qw) * 64;
    short8 aq0 = *(const short8*)(qbase + (size_t)l15 * 64 + quad * 8);
    short8 aq1 = *(const short8*)(qbase + (size_t)l15 * 64 + 32 + quad * 8);

    const unsigned short* kbase = kb + (size_t)(b * 8 + hkv) * 2048 * 64;
    const unsigned short* vbase = vt + (size_t)(b * 8 + hkv) * 64 * 2048;

    f32x4 O[4];
#pragma unroll
    for (int i = 0; i < 4; i++) O[i] = f32x4{0.f, 0.f, 0.f, 0.f};
    float lrow[4] = {0.f, 0.f, 0.f, 0.f};

    int kstart = qw - 511;
    if (kstart < 0) kstart = 0;
    kstart &= ~31;
    unsigned short* Pw = P[w];

    for (int k0 = kstart; k0 <= qw + 15; k0 += 32) {
        f32x4 S[2];
#pragma unroll
        for (int c = 0; c < 2; c++) {
            const unsigned short* kp = kbase + (size_t)(k0 + c * 16 + l15) * 64 + quad * 8;
            short8 kf0 = *(const short8*)kp;
            short8 kf1 = *(const short8*)(kp + 32);
            f32x4 s = __builtin_amdgcn_mfma_f32_16x16x32_bf16(aq0, kf0, f32x4{0.f, 0.f, 0.f, 0.f}, 0, 0, 0);
            s = __builtin_amdgcn_mfma_f32_16x16x32_bf16(aq1, kf1, s, 0, 0, 0);
            S[c] = s;
        }
        float p[2][4];
#pragma unroll
        for (int c = 0; c < 2; c++)
#pragma unroll
            for (int r = 0; r < 4; r++) {
                int i = qw + quad * 4 + r;
                int j = k0 + c * 16 + l15;
                // y = 50*tanh(S*0.125/50); |y| <= 50 so exp(y) is fp32/bf16-safe with m=0
                float tt = S[c][r] * (0.125f * 0.02f);
                tt = fminf(8.f, fmaxf(-8.f, tt));
                float e = __expf(2.f * tt);
                float y = 50.f * (e - 1.f) / (e + 1.f);
                bool ok = (j <= i) && ((i - j) < 512);
                p[c][r] = ok ? __expf(y) : 0.f;
            }
#pragma unroll
        for (int r = 0; r < 4; r++) {
            float rs = p[0][r] + p[1][r];
#pragma unroll
            for (int mm = 8; mm; mm >>= 1) rs += __shfl_xor(rs, mm, 16);
            lrow[r] += rs;
        }
#pragma unroll
        for (int c = 0; c < 2; c++)
#pragma unroll
            for (int r = 0; r < 4; r++)
                Pw[(quad * 4 + r) * 32 + c * 16 + l15] = f2bf(p[c][r]);
        asm volatile("s_waitcnt lgkmcnt(0)" ::: "memory");
        short8 pf = *(const short8*)&Pw[l15 * 32 + quad * 8];
#pragma unroll
        for (int ni = 0; ni < 4; ni++) {
            short8 vf = *(const short8*)(vbase + (size_t)(ni * 16 + l15) * 2048 + k0 + quad * 8);
            O[ni] = __builtin_amdgcn_mfma_f32_16x16x32_bf16(pf, vf, O[ni], 0, 0, 0);
        }
        asm volatile("s_waitcnt lgkmcnt(0)" ::: "memory");
    }
#pragma unroll
    for (int r = 0; r < 4; r++) {
        float inv = 1.f / lrow[r];
        int i = qw + quad * 4 + r;
        size_t tok = (size_t)b * 2048 + i;
#pragma unroll
        for (int ni = 0; ni < 4; ni++)
            ctx[tok * 1024 + H * 64 + ni * 16 + l15] = f2bf(O[ni][r] * inv);
    }
}

// ---------------- launch ----------------
extern "C" void kernel_launch(void* const* d_in, const int* in_sizes, int n_in,
                              void* d_out, int out_size, void* d_ws, size_t ws_size,
                              hipStream_t stream) {
    const float* x = (const float*)d_in[0];
    const float* ksum = (const float*)d_in[1];
    const float* rms1_scale = (const float*)d_in[2];
    const float* q_kernel = (const float*)d_in[3];
    const float* k_kernel = (const float*)d_in[4];
    const float* v_kernel = (const float*)d_in[5];
    const float* out_kernel = (const float*)d_in[6];
    const float* rms2_scale = (const float*)d_in[7];
    const float* gate_kernel = (const float*)d_in[8];
    const float* up_kernel = (const float*)d_in[9];
    const float* down_kernel = (const float*)d_in[10];

    char* ws = (char*)d_ws;
    unsigned short* wqkv = (unsigned short*)(ws + OFF_WQKV);
    unsigned short* wout = (unsigned short*)(ws + OFF_WOUT);
    unsigned short* wgate = (unsigned short*)(ws + OFF_WGATE);
    unsigned short* wup = (unsigned short*)(ws + OFF_WUP);
    unsigned short* wdown = (unsigned short*)(ws + OFF_WDOWN);
    unsigned short* xn1 = (unsigned short*)(ws + OFF_XN1);
    unsigned short* qkvp = (unsigned short*)(ws + OFF_QKVP);
    unsigned short* p2 = (unsigned short*)(ws + OFF_P2);
    unsigned short* p4 = (unsigned short*)(ws + OFF_P4);
    unsigned short* qb = (unsigned short*)(ws + OFF_QB);
    unsigned short* kb = (unsigned short*)(ws + OFF_KB);
    unsigned short* vtb = (unsigned short*)(ws + OFF_VT);
    unsigned short* ctx = (unsigned short*)(ws + OFF_CTX);
    float* x2 = (float*)(ws + OFF_X2);
    unsigned short* xn2 = (unsigned short*)(ws + OFF_XN2);
    unsigned short* g = (unsigned short*)(ws + OFF_G);
    float* outx = (float*)d_out;
    float* outk = outx + (size_t)NTOK * C;

    // prep: weight transpose+cast + rms1 (one launch)
    prep_kernel<<<15360 + NTOK, 256, 0, stream>>>(
        q_kernel, k_kernel, v_kernel, out_kernel, gate_kernel, up_kernel, down_kernel,
        wqkv, wout, wgate, wup, wdown, x, rms1_scale, xn1);

    // QKV projection, split-K=2 -> bf16 partials 2x[4096][2048]
    gemm128<4><<<dim3(2048 / 128, NTOK / 128, 2), 256, 0, stream>>>(
        xn1, wqkv, qkvp, 2048, 512, 1024, 1024, 512, 512, (size_t)NTOK * 2048);

    // partial-sum + RoPE scatter + V transpose (one launch)
    ropevt_kernel<<<NTOK + 512, 256, 0, stream>>>(qkvp, qb, kb, vtb);

    // attention
    attn_kernel<<<dim3(T / 64, NH, Bsz), 256, 0, stream>>>(qb, kb, vtb, ctx);

    // out projection, split-K=4 bf16 partials, then fused residual+rms2 (+kurt init)
    gemm128<4><<<dim3(1024 / 128, NTOK / 128, 4), 256, 0, stream>>>(
        ctx, wout, p2, 1024, 256, 1024, 1024, 256, 256, (size_t)NTOK * 1024);
    reduce_out<<<NTOK, 256, 0, stream>>>(p2, x, rms2_scale, x2, xn2, ksum, outk);

    // fused gate+up 128x64 -> g = silu(gate)*up, bf16 [4096][4096]
    gateup_kernel<<<dim3(HID / 64, NTOK / 128), 256, 0, stream>>>(xn2, wgate, wup, g);

    // down projection, split-K=4 bf16 partials, then fused residual+kurtosis
    gemm128<4><<<dim3(1024 / 128, NTOK / 128, 4), 256, 0, stream>>>(
        g, wdown, p4, 1024, 1024, 4096, 4096, 1024, 1024, (size_t)NTOK * 1024);
    reduce_down<<<NTOK, 256, 0, stream>>>(p4, x2, outx, outk);

    (void)in_sizes; (void)n_in; (void)out_size; (void)ws_size;
}

// Round 7
// 385.747 us; speedup vs baseline: 1.3600x; 1.1669x over previous
//
#include <hip/hip_runtime.h>
#include <hip/hip_bf16.h>

typedef __attribute__((ext_vector_type(8))) short short8;
typedef __attribute__((ext_vector_type(4))) float f32x4;
typedef __attribute__((ext_vector_type(4))) int int4v;
typedef __attribute__((ext_vector_type(8))) int int8v;

#define DEVFN static __device__ __forceinline__

DEVFN float bf2f(unsigned short u) {
    unsigned int i = ((unsigned int)u) << 16;
    float f; __builtin_memcpy(&f, &i, 4); return f;
}
DEVFN unsigned short f2bf(float f) {
    unsigned int i; __builtin_memcpy(&i, &f, 4);
    unsigned int r = i + 0x7fffu + ((i >> 16) & 1u);
    return (unsigned short)(r >> 16);
}
DEVFN unsigned char f2fp8(float f) {
    int r = __builtin_amdgcn_cvt_pk_fp8_f32(f, f, 0, false);
    return (unsigned char)(r & 0xff);
}

DEVFN void load_lds16(const void* g, void* l) {
    __builtin_amdgcn_global_load_lds(
        (__attribute__((address_space(1))) void*)g,
        (__attribute__((address_space(3))) void*)l, 16, 0, 0);
}

DEVFN f32x4 mfma_fp8(int8v a, int8v b, f32x4 c) {
    // cbsz=0 (A=fp8 e4m3), blgp=0 (B=fp8 e4m3), scales = 1.0 (e8m0 127)
    return __builtin_amdgcn_mfma_scale_f32_16x16x128_f8f6f4(
        a, b, c, 0, 0, 0, 0x7F7F7F7F, 0, 0x7F7F7F7F);
}

// ---------------- constants ----------------
constexpr int Bsz = 2, T = 2048, C = 1024;
constexpr int NH = 16, NKV = 8, HD = 64;
constexpr int HID = 4096;
constexpr int NTOK = Bsz * T;              // 4096
constexpr size_t MiB = 1024 * 1024;

// workspace offsets (bytes)
constexpr size_t OFF_WQKV = 0;             // bf16 [2048][1024]   4 MiB
constexpr size_t OFF_WOUT = 4 * MiB;       // bf16 [1024][1024]   2 MiB
constexpr size_t OFF_WGATE = 6 * MiB;      // fp8  [4096][1024]   4 MiB (x16)
constexpr size_t OFF_WUP = 10 * MiB;       // fp8  [4096][1024]   4 MiB (x16)
constexpr size_t OFF_WDOWN = 14 * MiB;     // fp8  [1024][4096]   4 MiB (x16)
constexpr size_t OFF_XN1 = 18 * MiB;       // bf16 [4096][1024]   8 MiB
constexpr size_t OFF_QKVP = 26 * MiB;      // bf16 2x[4096][2048] 32 MiB (dead after ropevt)
constexpr size_t OFF_P2 = 26 * MiB;        // bf16 4x[4096][1024] 32 MiB (reuses QKVP)
constexpr size_t OFF_QB = 58 * MiB;        // bf16 [2][16][2048][64] 8 MiB
constexpr size_t OFF_KB = 66 * MiB;        // bf16 [2][8][2048][64]  4 MiB
constexpr size_t OFF_VT = 70 * MiB;        // bf16 [2][8][64][2048]  4 MiB
constexpr size_t OFF_CTX = 74 * MiB;       // bf16 [4096][1024]   8 MiB
constexpr size_t OFF_X2 = 82 * MiB;        // f32  [4096][1024]  16 MiB
constexpr size_t OFF_XN2 = 98 * MiB;       // fp8  [4096][1024]   4 MiB (x4)
constexpr size_t OFF_G = 102 * MiB;        // fp8  [4096][4096]  16 MiB (x8)
constexpr size_t OFF_P4 = 118 * MiB;       // bf16 4x[4096][1024] 32 MiB
// total 150 MiB

// ---------------- prep: weight cast+transpose (7 mats) + rms1, one launch ----------------
// blocks [0,15360): transpose 32x32 tiles; [15360,19456): rms rows
__global__ __launch_bounds__(256) void prep_kernel(
    const float* __restrict__ qk, const float* __restrict__ kk2,
    const float* __restrict__ vk, const float* __restrict__ ok,
    const float* __restrict__ gk, const float* __restrict__ uk,
    const float* __restrict__ dk,
    unsigned short* __restrict__ wqkv, unsigned short* __restrict__ wout,
    unsigned char* __restrict__ wgate, unsigned char* __restrict__ wup,
    unsigned char* __restrict__ wdown,
    const float* __restrict__ x, const float* __restrict__ rms1_scale,
    unsigned short* __restrict__ xn1) {
    __shared__ float t[32][33];
    __shared__ float red[4];
    int id = blockIdx.x;
    int tid = threadIdx.x;
    if (id >= 15360) {
        int row = id - 15360;
        const float4 v = *(const float4*)&x[(size_t)row * 1024 + tid * 4];
        float ss = v.x * v.x + v.y * v.y + v.z * v.z + v.w * v.w;
#pragma unroll
        for (int m = 32; m; m >>= 1) ss += __shfl_xor(ss, m, 64);
        if ((tid & 63) == 0) red[tid >> 6] = ss;
        __syncthreads();
        float tot = red[0] + red[1] + red[2] + red[3];
        float inv = rsqrtf(tot * (1.f / 1024.f) + 1e-6f);
        const float4 sc = *(const float4*)&rms1_scale[tid * 4];
        size_t o = (size_t)row * 1024 + tid * 4;
        xn1[o + 0] = f2bf(v.x * inv * (1.f + sc.x));
        xn1[o + 1] = f2bf(v.y * inv * (1.f + sc.y));
        xn1[o + 2] = f2bf(v.z * inv * (1.f + sc.z));
        xn1[o + 3] = f2bf(v.w * inv * (1.f + sc.w));
        return;
    }
    const float* in; int K, N, nx, base; int fp8 = 0;
    unsigned short* out16 = nullptr; unsigned char* out8 = nullptr;
    if (id < 1024)       { in = qk;  out16 = wqkv;                       K = 1024; N = 1024; nx = 32;  base = 0; }
    else if (id < 1536)  { in = kk2; out16 = wqkv + (size_t)1024 * 1024; K = 1024; N = 512;  nx = 16;  base = 1024; }
    else if (id < 2048)  { in = vk;  out16 = wqkv + (size_t)1536 * 1024; K = 1024; N = 512;  nx = 16;  base = 1536; }
    else if (id < 3072)  { in = ok;  out16 = wout;                       K = 1024; N = 1024; nx = 32;  base = 2048; }
    else if (id < 7168)  { in = gk;  out8 = wgate; fp8 = 1;              K = 1024; N = 4096; nx = 128; base = 3072; }
    else if (id < 11264) { in = uk;  out8 = wup; fp8 = 1;                K = 1024; N = 4096; nx = 128; base = 7168; }
    else                 { in = dk;  out8 = wdown; fp8 = 1;              K = 4096; N = 1024; nx = 32;  base = 11264; }
    int lid = id - base;
    int n0 = (lid % nx) * 32, k0 = (lid / nx) * 32;
    int tx = tid & 31, ty = tid >> 5;
#pragma unroll
    for (int i = 0; i < 4; i++)
        t[ty + 8 * i][tx] = in[(size_t)(k0 + ty + 8 * i) * N + n0 + tx];
    __syncthreads();
    if (fp8) {
#pragma unroll
        for (int i = 0; i < 4; i++)
            out8[(size_t)(n0 + ty + 8 * i) * K + k0 + tx] = f2fp8(t[tx][ty + 8 * i] * 16.f);
    } else {
#pragma unroll
        for (int i = 0; i < 4; i++)
            out16[(size_t)(n0 + ty + 8 * i) * K + k0 + tx] = f2bf(t[tx][ty + 8 * i]);
    }
}

// ---------------- bf16 GEMM (qkv, out-proj): C = A @ Bt^T ----------------
__global__ __launch_bounds__(256) void gemm128(const unsigned short* __restrict__ A,
                                               const unsigned short* __restrict__ Bt,
                                               unsigned short* __restrict__ Cp,
                                               int N, int K, int lda, int ldb,
                                               size_t zA, size_t zB, size_t zC) {
    __shared__ __align__(16) unsigned short As[128 * 32];
    __shared__ __align__(16) unsigned short Bs[128 * 32];
    A += (size_t)blockIdx.z * zA;
    Bt += (size_t)blockIdx.z * zB;
    const int tid = threadIdx.x;
    const int lane = tid & 63, w = tid >> 6;
    const int quad = lane >> 4, l15 = lane & 15;
    const int wr = w >> 1, wc = w & 1;
    const int m0 = blockIdx.y * 128, n0 = blockIdx.x * 128;

    f32x4 acc[4][4];
#pragma unroll
    for (int i = 0; i < 4; i++)
#pragma unroll
        for (int j = 0; j < 4; j++) acc[i][j] = f32x4{0.f, 0.f, 0.f, 0.f};

    const int stRow = (w << 4) + (lane >> 2);
    const int stCol = (lane & 3) << 3;

    for (int kk = 0; kk < K; kk += 32) {
#pragma unroll
        for (int i = 0; i < 2; i++) {
            load_lds16(A + (size_t)(m0 + (i << 6) + stRow) * lda + kk + stCol,
                       &As[((i << 6) + (w << 4)) * 32]);
            load_lds16(Bt + (size_t)(n0 + (i << 6) + stRow) * ldb + kk + stCol,
                       &Bs[((i << 6) + (w << 4)) * 32]);
        }
        __syncthreads();
        short8 a[4], b[4];
#pragma unroll
        for (int mi = 0; mi < 4; mi++)
            a[mi] = *(const short8*)&As[(wr * 64 + mi * 16 + l15) * 32 + quad * 8];
#pragma unroll
        for (int ni = 0; ni < 4; ni++)
            b[ni] = *(const short8*)&Bs[(wc * 64 + ni * 16 + l15) * 32 + quad * 8];
#pragma unroll
        for (int mi = 0; mi < 4; mi++)
#pragma unroll
            for (int ni = 0; ni < 4; ni++)
                acc[mi][ni] = __builtin_amdgcn_mfma_f32_16x16x32_bf16(a[mi], b[ni], acc[mi][ni], 0, 0, 0);
        __syncthreads();
    }
#pragma unroll
    for (int mi = 0; mi < 4; mi++)
#pragma unroll
        for (int ni = 0; ni < 4; ni++)
#pragma unroll
            for (int r = 0; r < 4; r++) {
                int row = m0 + wr * 64 + mi * 16 + quad * 4 + r;
                int col = n0 + wc * 64 + ni * 16 + l15;
                Cp[(size_t)blockIdx.z * zC + (size_t)row * N + col] = f2bf(acc[mi][ni][r]);
            }
}

// ---------------- fp8 fragment helpers (XOR half-swizzled LDS) ----------------
DEVFN int8v read_frag8(const unsigned char* buf, int rb, int quad) {
    int base = rb * 128;
    int h0 = (2 * quad) ^ (rb & 7);
    int h1 = (2 * quad + 1) ^ (rb & 7);
    int4v lo = *(const int4v*)&buf[base + h0 * 16];
    int4v hi = *(const int4v*)&buf[base + h1 * 16];
    return int8v{lo.x, lo.y, lo.z, lo.w, hi.x, hi.y, hi.z, hi.w};
}

// ---------------- fused gate+up GEMM, fp8 MX K=128: 128x64 tile of both ----------------
// A = xn2 fp8 (x4), Bg/Bu = weights fp8 (x16) -> acc/64; out = fp8(silu(g)*u * 8)
__global__ __launch_bounds__(256) void gateup_kernel(const unsigned char* __restrict__ A,
                                                     const unsigned char* __restrict__ Bg,
                                                     const unsigned char* __restrict__ Bu,
                                                     unsigned char* __restrict__ out) {
    __shared__ __align__(16) unsigned char As[128 * 128];
    __shared__ __align__(16) unsigned char Gs[64 * 128];
    __shared__ __align__(16) unsigned char Us[64 * 128];
    const int tid = threadIdx.x;
    const int lane = tid & 63, w = tid >> 6;
    const int quad = lane >> 4, l15 = lane & 15;
    const int wr = w >> 1, wc = w & 1;
    const int m0 = blockIdx.y * 128, n0 = blockIdx.x * 64;

    f32x4 aG[4][2], aU[4][2];
#pragma unroll
    for (int i = 0; i < 4; i++)
#pragma unroll
        for (int j = 0; j < 2; j++) { aG[i][j] = f32x4{0.f, 0.f, 0.f, 0.f}; aU[i][j] = f32x4{0.f, 0.f, 0.f, 0.f}; }

    const int lrow = lane >> 3;        // row within 8-row issue
    const int hA = (lane & 7) ^ lrow;  // swizzled half

    for (int kk = 0; kk < 1024; kk += 128) {
#pragma unroll
        for (int j = 0; j < 4; j++) {
            int i = w * 4 + j;                 // A: rows 8i..8i+7
            int r = i * 8 + lrow;
            load_lds16(A + (size_t)(m0 + r) * 1024 + kk + hA * 16, &As[i * 1024]);
        }
#pragma unroll
        for (int j = 0; j < 2; j++) {
            int i = w * 2 + j;                 // B: rows 8i..8i+7 (64 total)
            int r = i * 8 + lrow;
            load_lds16(Bg + (size_t)(n0 + r) * 1024 + kk + hA * 16, &Gs[i * 1024]);
            load_lds16(Bu + (size_t)(n0 + r) * 1024 + kk + hA * 16, &Us[i * 1024]);
        }
        __syncthreads();
        int8v a[4], bg[2], bu[2];
#pragma unroll
        for (int mi = 0; mi < 4; mi++)
            a[mi] = read_frag8(As, wr * 64 + mi * 16 + l15, quad);
#pragma unroll
        for (int ni = 0; ni < 2; ni++) {
            bg[ni] = read_frag8(Gs, wc * 32 + ni * 16 + l15, quad);
            bu[ni] = read_frag8(Us, wc * 32 + ni * 16 + l15, quad);
        }
#pragma unroll
        for (int mi = 0; mi < 4; mi++)
#pragma unroll
            for (int ni = 0; ni < 2; ni++) {
                aG[mi][ni] = mfma_fp8(a[mi], bg[ni], aG[mi][ni]);
                aU[mi][ni] = mfma_fp8(a[mi], bu[ni], aU[mi][ni]);
            }
        __syncthreads();
    }
#pragma unroll
    for (int mi = 0; mi < 4; mi++)
#pragma unroll
        for (int ni = 0; ni < 2; ni++)
#pragma unroll
            for (int r = 0; r < 4; r++) {
                int row = m0 + wr * 64 + mi * 16 + quad * 4 + r;
                int col = n0 + wc * 32 + ni * 16 + l15;
                float vg = aG[mi][ni][r] * (1.f / 64.f);
                float vu = aU[mi][ni][r] * (1.f / 64.f);
                float s = vg / (1.f + __expf(-vg));
                out[(size_t)row * 4096 + col] = f2fp8(s * vu * 8.f);
            }
}

// ---------------- down GEMM, fp8 MX K=128, split-K=4, bf16 partials ----------------
// A = g fp8 (x8) [4096][4096], Bt = wdown fp8 (x16) [1024][4096] -> acc/128
__global__ __launch_bounds__(256) void down_gemm(const unsigned char* __restrict__ A,
                                                 const unsigned char* __restrict__ Bt,
                                                 unsigned short* __restrict__ Cp) {
    __shared__ __align__(16) unsigned char As[128 * 128];
    __shared__ __align__(16) unsigned char Bs[128 * 128];
    const int tid = threadIdx.x;
    const int lane = tid & 63, w = tid >> 6;
    const int quad = lane >> 4, l15 = lane & 15;
    const int wr = w >> 1, wc = w & 1;
    const int m0 = blockIdx.y * 128, n0 = blockIdx.x * 128;
    const int kbase = blockIdx.z * 1024;

    f32x4 acc[4][4];
#pragma unroll
    for (int i = 0; i < 4; i++)
#pragma unroll
        for (int j = 0; j < 4; j++) acc[i][j] = f32x4{0.f, 0.f, 0.f, 0.f};

    const int lrow = lane >> 3;
    const int hA = (lane & 7) ^ lrow;

    for (int kk = 0; kk < 1024; kk += 128) {
#pragma unroll
        for (int j = 0; j < 4; j++) {
            int i = w * 4 + j;
            int r = i * 8 + lrow;
            load_lds16(A + (size_t)(m0 + r) * 4096 + kbase + kk + hA * 16, &As[i * 1024]);
            load_lds16(Bt + (size_t)(n0 + r) * 4096 + kbase + kk + hA * 16, &Bs[i * 1024]);
        }
        __syncthreads();
        int8v a[4], b[4];
#pragma unroll
        for (int mi = 0; mi < 4; mi++)
            a[mi] = read_frag8(As, wr * 64 + mi * 16 + l15, quad);
#pragma unroll
        for (int ni = 0; ni < 4; ni++)
            b[ni] = read_frag8(Bs, wc * 64 + ni * 16 + l15, quad);
#pragma unroll
        for (int mi = 0; mi < 4; mi++)
#pragma unroll
            for (int ni = 0; ni < 4; ni++)
                acc[mi][ni] = mfma_fp8(a[mi], b[ni], acc[mi][ni]);
        __syncthreads();
    }
    const size_t Z = (size_t)NTOK * 1024;
#pragma unroll
    for (int mi = 0; mi < 4; mi++)
#pragma unroll
        for (int ni = 0; ni < 4; ni++)
#pragma unroll
            for (int r = 0; r < 4; r++) {
                int row = m0 + wr * 64 + mi * 16 + quad * 4 + r;
                int col = n0 + wc * 64 + ni * 16 + l15;
                Cp[(size_t)blockIdx.z * Z + (size_t)row * 1024 + col] =
                    f2bf(acc[mi][ni][r] * (1.f / 128.f));
            }
}

// ---------------- out-proj reduce: x2 = sum(p[0..3]) + x; xn2 = fp8(rms*4); init outk ----------------
__global__ __launch_bounds__(256) void reduce_out(const unsigned short* __restrict__ p,
                                                  const float* __restrict__ x,
                                                  const float* __restrict__ scale,
                                                  float* __restrict__ x2,
                                                  unsigned char* __restrict__ xn2,
                                                  const float* __restrict__ ksum,
                                                  float* __restrict__ outk) {
    __shared__ float red[4];
    int row = blockIdx.x, tid = threadIdx.x;
    if (row == 0 && tid == 0) outk[0] = ksum[0];
    size_t base = (size_t)row * 1024 + tid * 4;
    const size_t Z = (size_t)NTOK * 1024;
    float4 v = *(const float4*)&x[base];
#pragma unroll
    for (int z = 0; z < 4; z++) {
        ushort4 u = *(const ushort4*)&p[base + z * Z];
        v.x += bf2f(u.x); v.y += bf2f(u.y); v.z += bf2f(u.z); v.w += bf2f(u.w);
    }
    *(float4*)&x2[base] = v;
    float ss = v.x * v.x + v.y * v.y + v.z * v.z + v.w * v.w;
#pragma unroll
    for (int m = 32; m; m >>= 1) ss += __shfl_xor(ss, m, 64);
    if ((tid & 63) == 0) red[tid >> 6] = ss;
    __syncthreads();
    float tot = red[0] + red[1] + red[2] + red[3];
    float inv = rsqrtf(tot * (1.f / 1024.f) + 1e-6f) * 4.f;   // x4 fp8 prescale
    const float4 sc = *(const float4*)&scale[tid * 4];
    xn2[base + 0] = f2fp8(v.x * inv * (1.f + sc.x));
    xn2[base + 1] = f2fp8(v.y * inv * (1.f + sc.y));
    xn2[base + 2] = f2fp8(v.z * inv * (1.f + sc.z));
    xn2[base + 3] = f2fp8(v.w * inv * (1.f + sc.w));
}

// ---------------- down reduce: out = sum(p[0..3]) + x2, fused kurtosis ----------------
__global__ __launch_bounds__(256) void reduce_down(const unsigned short* __restrict__ p,
                                                   const float* __restrict__ x2,
                                                   float* __restrict__ outx,
                                                   float* __restrict__ outk) {
    __shared__ float red[4], r2[4], r4[4];
    int row = blockIdx.x, tid = threadIdx.x;
    size_t base = (size_t)row * 1024 + tid * 4;
    const size_t Z = (size_t)NTOK * 1024;
    float4 v = *(const float4*)&x2[base];
#pragma unroll
    for (int z = 0; z < 4; z++) {
        ushort4 u = *(const ushort4*)&p[base + z * Z];
        v.x += bf2f(u.x); v.y += bf2f(u.y); v.z += bf2f(u.z); v.w += bf2f(u.w);
    }
    *(float4*)&outx[base] = v;
    float s = v.x + v.y + v.z + v.w;
#pragma unroll
    for (int m = 32; m; m >>= 1) s += __shfl_xor(s, m, 64);
    if ((tid & 63) == 0) red[tid >> 6] = s;
    __syncthreads();
    float mean = (red[0] + red[1] + red[2] + red[3]) * (1.f / 1024.f);
    float cx = v.x - mean, cy = v.y - mean, cz = v.z - mean, cw = v.w - mean;
    float x2v = cx * cx, y2 = cy * cy, z2 = cz * cz, w2 = cw * cw;
    float c2 = x2v + y2 + z2 + w2;
    float c4 = x2v * x2v + y2 * y2 + z2 * z2 + w2 * w2;
#pragma unroll
    for (int m = 32; m; m >>= 1) {
        c2 += __shfl_xor(c2, m, 64);
        c4 += __shfl_xor(c4, m, 64);
    }
    if ((tid & 63) == 0) { r2[tid >> 6] = c2; r4[tid >> 6] = c4; }
    __syncthreads();
    if (tid == 0) {
        float m2 = (r2[0] + r2[1] + r2[2] + r2[3]) * (1.f / 1024.f);
        float m4 = (r4[0] + r4[1] + r4[2] + r4[3]) * (1.f / 1024.f);
        float kurt = m4 / (m2 * m2 + 1e-6f) - 3.f;
        if (kurt > 0.f) atomicAdd(outk, kurt);
    }
}

// ---------------- ropevt: reduce qkv split-K partials + RoPE scatter + V transpose ----------------
__global__ __launch_bounds__(256) void ropevt_kernel(const unsigned short* __restrict__ qkvp,
                                                     unsigned short* __restrict__ qb,
                                                     unsigned short* __restrict__ kb,
                                                     unsigned short* __restrict__ vt) {
    __shared__ float sv[32], cv[32];
    __shared__ unsigned short tile[64][68];
    const size_t Z = (size_t)NTOK * 2048;
    int id = blockIdx.x;
    int tid = threadIdx.x;
    if (id < NTOK) {
        int tok = id;
        int b = tok >> 11, t = tok & 2047;
        if (tid < 32) {
            float fr = (float)tid * (1.f / 32.f);
            float freq = powf(1e6f, -fr);
            float a = (float)t * freq;
            sv[tid] = sinf(a);
            cv[tid] = cosf(a);
        }
        __syncthreads();
        const unsigned short* r0 = qkvp + (size_t)tok * 2048;
        const unsigned short* r1 = r0 + Z;
#pragma unroll
        for (int e = tid; e < 1536; e += 256) {
            int u = e >> 6, d = e & 63;
            int col = (u < 16) ? (u * 64 + d) : (1024 + (u - 16) * 64 + d);
            int pcol = (d < 32) ? col + 32 : col - 32;
            float sgn = (d < 32) ? -1.f : 1.f;
            float vc = bf2f(r0[col]) + bf2f(r1[col]);
            float vp = bf2f(r0[pcol]) + bf2f(r1[pcol]);
            float o = vc * cv[d & 31] + sgn * vp * sv[d & 31];
            if (u < 16)
                qb[((size_t)(b * 16 + u) * 2048 + t) * 64 + d] = f2bf(o);
            else
                kb[((size_t)(b * 8 + (u - 16)) * 2048 + t) * 64 + d] = f2bf(o);
        }
    } else {
        int lid = id - NTOK;
        int b = lid >> 8, h = (lid >> 5) & 7, t0 = (lid & 31) * 64;
        int d = tid & 63, tr = tid >> 6;
#pragma unroll
        for (int i = 0; i < 16; i++) {
            int t = tr + i * 4;
            size_t gi = (size_t)(b * 2048 + t0 + t) * 2048 + 1536 + h * 64 + d;
            tile[t][d] = f2bf(bf2f(qkvp[gi]) + bf2f(qkvp[gi + Z]));
        }
        __syncthreads();
        int tt = tid & 63, dr = tid >> 6;
#pragma unroll
        for (int i = 0; i < 16; i++) {
            int dd = dr + i * 4;
            vt[((size_t)(b * 8 + h) * 64 + dd) * 2048 + t0 + tt] = tile[tt][dd];
        }
    }
}

// ---------------- flash attention, sliding window, soft cap; fixed-m softmax ----------------
__global__ __launch_bounds__(256) void attn_kernel(const unsigned short* __restrict__ qb,
                                                   const unsigned short* __restrict__ kb,
                                                   const unsigned short* __restrict__ vt,
                                                   unsigned short* __restrict__ ctx) {
    __shared__ __align__(16) unsigned short P[4][16 * 32];
    const int tid = threadIdx.x, lane = tid & 63, w = tid >> 6;
    const int quad = lane >> 4, l15 = lane & 15;
    const int qt = blockIdx.x, H = blockIdx.y, b = blockIdx.z;
    const int hkv = H & 7;
    const int qw = qt * 64 + w * 16;

    const unsigned short* qbase = qb + ((size_t)(b * 16 + H) * 2048 + qw) * 64;
    short8 aq0 = *(const short8*)(qbase + (size_t)l15 * 64 + quad * 8);
    short8 aq1 = *(const short8*)(qbase + (size_t)l15 * 64 + 32 + quad * 8);

    const unsigned short* kbase = kb + (size_t)(b * 8 + hkv) * 2048 * 64;
    const unsigned short* vbase = vt + (size_t)(b * 8 + hkv) * 64 * 2048;

    f32x4 O[4];
#pragma unroll
    for (int i = 0; i < 4; i++) O[i] = f32x4{0.f, 0.f, 0.f, 0.f};
    float lrow[4] = {0.f, 0.f, 0.f, 0.f};

    int kstart = qw - 511;
    if (kstart < 0) kstart = 0;
    kstart &= ~31;
    unsigned short* Pw = P[w];

    for (int k0 = kstart; k0 <= qw + 15; k0 += 32) {
        f32x4 S[2];
#pragma unroll
        for (int c = 0; c < 2; c++) {
            const unsigned short* kp = kbase + (size_t)(k0 + c * 16 + l15) * 64 + quad * 8;
            short8 kf0 = *(const short8*)kp;
            short8 kf1 = *(const short8*)(kp + 32);
            f32x4 s = __builtin_amdgcn_mfma_f32_16x16x32_bf16(aq0, kf0, f32x4{0.f, 0.f, 0.f, 0.f}, 0, 0, 0);
            s = __builtin_amdgcn_mfma_f32_16x16x32_bf16(aq1, kf1, s, 0, 0, 0);
            S[c] = s;
        }
        float p[2][4];
#pragma unroll
        for (int c = 0; c < 2; c++)
#pragma unroll
            for (int r = 0; r < 4; r++) {
                int i = qw + quad * 4 + r;
                int j = k0 + c * 16 + l15;
                float tt = S[c][r] * (0.125f * 0.02f);
                tt = fminf(8.f, fmaxf(-8.f, tt));
                float e = __expf(2.f * tt);
                float y = 50.f * (e - 1.f) / (e + 1.f);
                bool ok = (j <= i) && ((i - j) < 512);
                p[c][r] = ok ? __expf(y) : 0.f;
            }
#pragma unroll
        for (int r = 0; r < 4; r++) {
            float rs = p[0][r] + p[1][r];
#pragma unroll
            for (int mm = 8; mm; mm >>= 1) rs += __shfl_xor(rs, mm, 16);
            lrow[r] += rs;
        }
#pragma unroll
        for (int c = 0; c < 2; c++)
#pragma unroll
            for (int r = 0; r < 4; r++)
                Pw[(quad * 4 + r) * 32 + c * 16 + l15] = f2bf(p[c][r]);
        asm volatile("s_waitcnt lgkmcnt(0)" ::: "memory");
        short8 pf = *(const short8*)&Pw[l15 * 32 + quad * 8];
#pragma unroll
        for (int ni = 0; ni < 4; ni++) {
            short8 vf = *(const short8*)(vbase + (size_t)(ni * 16 + l15) * 2048 + k0 + quad * 8);
            O[ni] = __builtin_amdgcn_mfma_f32_16x16x32_bf16(pf, vf, O[ni], 0, 0, 0);
        }
        asm volatile("s_waitcnt lgkmcnt(0)" ::: "memory");
    }
#pragma unroll
    for (int r = 0; r < 4; r++) {
        float inv = 1.f / lrow[r];
        int i = qw + quad * 4 + r;
        size_t tok = (size_t)b * 2048 + i;
#pragma unroll
        for (int ni = 0; ni < 4; ni++)
            ctx[tok * 1024 + H * 64 + ni * 16 + l15] = f2bf(O[ni][r] * inv);
    }
}

// ---------------- launch ----------------
extern "C" void kernel_launch(void* const* d_in, const int* in_sizes, int n_in,
                              void* d_out, int out_size, void* d_ws, size_t ws_size,
                              hipStream_t stream) {
    const float* x = (const float*)d_in[0];
    const float* ksum = (const float*)d_in[1];
    const float* rms1_scale = (const float*)d_in[2];
    const float* q_w = (const float*)d_in[3];
    const float* k_w = (const float*)d_in[4];
    const float* v_w = (const float*)d_in[5];
    const float* out_w = (const float*)d_in[6];
    const float* rms2_scale = (const float*)d_in[7];
    const float* gate_w = (const float*)d_in[8];
    const float* up_w = (const float*)d_in[9];
    const float* down_w = (const float*)d_in[10];

    char* ws = (char*)d_ws;
    unsigned short* wqkv = (unsigned short*)(ws + OFF_WQKV);
    unsigned short* wout = (unsigned short*)(ws + OFF_WOUT);
    unsigned char* wgate = (unsigned char*)(ws + OFF_WGATE);
    unsigned char* wup = (unsigned char*)(ws + OFF_WUP);
    unsigned char* wdown = (unsigned char*)(ws + OFF_WDOWN);
    unsigned short* xn1 = (unsigned short*)(ws + OFF_XN1);
    unsigned short* qkvp = (unsigned short*)(ws + OFF_QKVP);
    unsigned short* p2 = (unsigned short*)(ws + OFF_P2);
    unsigned short* qb = (unsigned short*)(ws + OFF_QB);
    unsigned short* kb = (unsigned short*)(ws + OFF_KB);
    unsigned short* vtb = (unsigned short*)(ws + OFF_VT);
    unsigned short* ctx = (unsigned short*)(ws + OFF_CTX);
    float* x2 = (float*)(ws + OFF_X2);
    unsigned char* xn2 = (unsigned char*)(ws + OFF_XN2);
    unsigned char* g = (unsigned char*)(ws + OFF_G);
    unsigned short* p4 = (unsigned short*)(ws + OFF_P4);
    float* outx = (float*)d_out;
    float* outk = outx + (size_t)NTOK * C;

    // prep: weight transpose+cast (bf16 qkv/out, fp8 x16 mlp) + rms1
    prep_kernel<<<15360 + NTOK, 256, 0, stream>>>(
        q_w, k_w, v_w, out_w, gate_w, up_w, down_w,
        wqkv, wout, wgate, wup, wdown, x, rms1_scale, xn1);

    // QKV projection, split-K=2 -> bf16 partials 2x[4096][2048]
    gemm128<<<dim3(2048 / 128, NTOK / 128, 2), 256, 0, stream>>>(
        xn1, wqkv, qkvp, 2048, 512, 1024, 1024, 512, 512, (size_t)NTOK * 2048);

    // partial-sum + RoPE scatter + V transpose
    ropevt_kernel<<<NTOK + 512, 256, 0, stream>>>(qkvp, qb, kb, vtb);

    // attention
    attn_kernel<<<dim3(T / 64, NH, Bsz), 256, 0, stream>>>(qb, kb, vtb, ctx);

    // out projection, split-K=4 bf16 partials, then fused residual+rms2(fp8 x4)+kurt init
    gemm128<<<dim3(1024 / 128, NTOK / 128, 4), 256, 0, stream>>>(
        ctx, wout, p2, 1024, 256, 1024, 1024, 256, 256, (size_t)NTOK * 1024);
    reduce_out<<<NTOK, 256, 0, stream>>>(p2, x, rms2_scale, x2, xn2, ksum, outk);

    // fused gate+up fp8 MX -> g = fp8(silu(gate)*up * 8)
    gateup_kernel<<<dim3(HID / 64, NTOK / 128), 256, 0, stream>>>(xn2, wgate, wup, g);

    // down projection fp8 MX, split-K=4 bf16 partials, then fused residual+kurtosis
    down_gemm<<<dim3(1024 / 128, NTOK / 128, 4), 256, 0, stream>>>(g, wdown, p4);
    reduce_down<<<NTOK, 256, 0, stream>>>(p4, x2, outx, outk);

    (void)in_sizes; (void)n_in; (void)out_size; (void)ws_size;
}

// Round 8
// 379.345 us; speedup vs baseline: 1.3830x; 1.0169x over previous
//
#include <hip/hip_runtime.h>
#include <hip/hip_bf16.h>

typedef __attribute__((ext_vector_type(8))) short short8;
typedef __attribute__((ext_vector_type(4))) float f32x4;
typedef __attribute__((ext_vector_type(4))) int int4v;
typedef __attribute__((ext_vector_type(8))) int int8v;

#define DEVFN static __device__ __forceinline__

DEVFN float bf2f(unsigned short u) {
    unsigned int i = ((unsigned int)u) << 16;
    float f; __builtin_memcpy(&f, &i, 4); return f;
}
DEVFN unsigned short f2bf(float f) {
    unsigned int i; __builtin_memcpy(&i, &f, 4);
    unsigned int r = i + 0x7fffu + ((i >> 16) & 1u);
    return (unsigned short)(r >> 16);
}
DEVFN unsigned char f2fp8(float f) {
    int r = __builtin_amdgcn_cvt_pk_fp8_f32(f, f, 0, false);
    return (unsigned char)(r & 0xff);
}
DEVFN float fastrcp(float x) { return __builtin_amdgcn_rcpf(x); }

DEVFN void load_lds16(const void* g, void* l) {
    __builtin_amdgcn_global_load_lds(
        (__attribute__((address_space(1))) void*)g,
        (__attribute__((address_space(3))) void*)l, 16, 0, 0);
}

DEVFN f32x4 mfma_fp8(int8v a, int8v b, f32x4 c) {
    // cbsz=0 (A=fp8 e4m3), blgp=0 (B=fp8 e4m3), scales = 1.0 (e8m0 127)
    return __builtin_amdgcn_mfma_scale_f32_16x16x128_f8f6f4(
        a, b, c, 0, 0, 0, 0x7F7F7F7F, 0, 0x7F7F7F7F);
}

// ---------------- constants ----------------
constexpr int Bsz = 2, T = 2048, C = 1024;
constexpr int NH = 16, NKV = 8, HD = 64;
constexpr int HID = 4096;
constexpr int NTOK = Bsz * T;              // 4096
constexpr size_t MiB = 1024 * 1024;

// workspace offsets (bytes)
constexpr size_t OFF_WQKV = 0;             // bf16 [2048][1024]   4 MiB
constexpr size_t OFF_WOUT = 4 * MiB;       // bf16 [1024][1024]   2 MiB
constexpr size_t OFF_WGATE = 6 * MiB;      // fp8  [4096][1024]   4 MiB (x16)
constexpr size_t OFF_WUP = 10 * MiB;       // fp8  [4096][1024]   4 MiB (x16)
constexpr size_t OFF_WDOWN = 14 * MiB;     // fp8  [1024][4096]   4 MiB (x16)
constexpr size_t OFF_XN1 = 18 * MiB;       // bf16 [4096][1024]   8 MiB
constexpr size_t OFF_QKVP = 26 * MiB;      // bf16 2x[4096][2048] 32 MiB (dead after ropevt)
constexpr size_t OFF_P2 = 26 * MiB;        // bf16 4x[4096][1024] 32 MiB (reuses QKVP)
constexpr size_t OFF_QB = 58 * MiB;        // bf16 [2][16][2048][64] 8 MiB
constexpr size_t OFF_KB = 66 * MiB;        // bf16 [2][8][2048][64]  4 MiB
constexpr size_t OFF_VT = 70 * MiB;        // bf16 [2][8][64][2048]  4 MiB
constexpr size_t OFF_CTX = 74 * MiB;       // bf16 [4096][1024]   8 MiB
constexpr size_t OFF_X2 = 82 * MiB;        // f32  [4096][1024]  16 MiB
constexpr size_t OFF_XN2 = 98 * MiB;       // fp8  [4096][1024]   4 MiB (x4)
constexpr size_t OFF_G = 102 * MiB;        // fp8  [4096][4096]  16 MiB (x8)
constexpr size_t OFF_P4 = 118 * MiB;       // bf16 4x[4096][1024] 32 MiB
// total 150 MiB

// ---------------- prep: weight cast+transpose (7 mats) + rms1, one launch ----------------
// blocks [0,15360): transpose 32x32 tiles; [15360,19456): rms rows
__global__ __launch_bounds__(256) void prep_kernel(
    const float* __restrict__ qk, const float* __restrict__ kk2,
    const float* __restrict__ vk, const float* __restrict__ ok,
    const float* __restrict__ gk, const float* __restrict__ uk,
    const float* __restrict__ dk,
    unsigned short* __restrict__ wqkv, unsigned short* __restrict__ wout,
    unsigned char* __restrict__ wgate, unsigned char* __restrict__ wup,
    unsigned char* __restrict__ wdown,
    const float* __restrict__ x, const float* __restrict__ rms1_scale,
    unsigned short* __restrict__ xn1) {
    __shared__ float t[32][33];
    __shared__ float red[4];
    int id = blockIdx.x;
    int tid = threadIdx.x;
    if (id >= 15360) {
        int row = id - 15360;
        const float4 v = *(const float4*)&x[(size_t)row * 1024 + tid * 4];
        float ss = v.x * v.x + v.y * v.y + v.z * v.z + v.w * v.w;
#pragma unroll
        for (int m = 32; m; m >>= 1) ss += __shfl_xor(ss, m, 64);
        if ((tid & 63) == 0) red[tid >> 6] = ss;
        __syncthreads();
        float tot = red[0] + red[1] + red[2] + red[3];
        float inv = rsqrtf(tot * (1.f / 1024.f) + 1e-6f);
        const float4 sc = *(const float4*)&rms1_scale[tid * 4];
        size_t o = (size_t)row * 1024 + tid * 4;
        xn1[o + 0] = f2bf(v.x * inv * (1.f + sc.x));
        xn1[o + 1] = f2bf(v.y * inv * (1.f + sc.y));
        xn1[o + 2] = f2bf(v.z * inv * (1.f + sc.z));
        xn1[o + 3] = f2bf(v.w * inv * (1.f + sc.w));
        return;
    }
    const float* in; int K, N, nx, base; int fp8 = 0;
    unsigned short* out16 = nullptr; unsigned char* out8 = nullptr;
    if (id < 1024)       { in = qk;  out16 = wqkv;                       K = 1024; N = 1024; nx = 32;  base = 0; }
    else if (id < 1536)  { in = kk2; out16 = wqkv + (size_t)1024 * 1024; K = 1024; N = 512;  nx = 16;  base = 1024; }
    else if (id < 2048)  { in = vk;  out16 = wqkv + (size_t)1536 * 1024; K = 1024; N = 512;  nx = 16;  base = 1536; }
    else if (id < 3072)  { in = ok;  out16 = wout;                       K = 1024; N = 1024; nx = 32;  base = 2048; }
    else if (id < 7168)  { in = gk;  out8 = wgate; fp8 = 1;              K = 1024; N = 4096; nx = 128; base = 3072; }
    else if (id < 11264) { in = uk;  out8 = wup; fp8 = 1;                K = 1024; N = 4096; nx = 128; base = 7168; }
    else                 { in = dk;  out8 = wdown; fp8 = 1;              K = 4096; N = 1024; nx = 32;  base = 11264; }
    int lid = id - base;
    int n0 = (lid % nx) * 32, k0 = (lid / nx) * 32;
    int tx = tid & 31, ty = tid >> 5;
#pragma unroll
    for (int i = 0; i < 4; i++)
        t[ty + 8 * i][tx] = in[(size_t)(k0 + ty + 8 * i) * N + n0 + tx];
    __syncthreads();
    if (fp8) {
#pragma unroll
        for (int i = 0; i < 4; i++)
            out8[(size_t)(n0 + ty + 8 * i) * K + k0 + tx] = f2fp8(t[tx][ty + 8 * i] * 16.f);
    } else {
#pragma unroll
        for (int i = 0; i < 4; i++)
            out16[(size_t)(n0 + ty + 8 * i) * K + k0 + tx] = f2bf(t[tx][ty + 8 * i]);
    }
}

// ---------------- bf16 GEMM (qkv, out-proj): C = A @ Bt^T ----------------
__global__ __launch_bounds__(256) void gemm128(const unsigned short* __restrict__ A,
                                               const unsigned short* __restrict__ Bt,
                                               unsigned short* __restrict__ Cp,
                                               int N, int K, int lda, int ldb,
                                               size_t zA, size_t zB, size_t zC) {
    __shared__ __align__(16) unsigned short As[128 * 32];
    __shared__ __align__(16) unsigned short Bs[128 * 32];
    A += (size_t)blockIdx.z * zA;
    Bt += (size_t)blockIdx.z * zB;
    const int tid = threadIdx.x;
    const int lane = tid & 63, w = tid >> 6;
    const int quad = lane >> 4, l15 = lane & 15;
    const int wr = w >> 1, wc = w & 1;
    const int m0 = blockIdx.y * 128, n0 = blockIdx.x * 128;

    f32x4 acc[4][4];
#pragma unroll
    for (int i = 0; i < 4; i++)
#pragma unroll
        for (int j = 0; j < 4; j++) acc[i][j] = f32x4{0.f, 0.f, 0.f, 0.f};

    const int stRow = (w << 4) + (lane >> 2);
    const int stCol = (lane & 3) << 3;

    for (int kk = 0; kk < K; kk += 32) {
#pragma unroll
        for (int i = 0; i < 2; i++) {
            load_lds16(A + (size_t)(m0 + (i << 6) + stRow) * lda + kk + stCol,
                       &As[((i << 6) + (w << 4)) * 32]);
            load_lds16(Bt + (size_t)(n0 + (i << 6) + stRow) * ldb + kk + stCol,
                       &Bs[((i << 6) + (w << 4)) * 32]);
        }
        __syncthreads();
        short8 a[4], b[4];
#pragma unroll
        for (int mi = 0; mi < 4; mi++)
            a[mi] = *(const short8*)&As[(wr * 64 + mi * 16 + l15) * 32 + quad * 8];
#pragma unroll
        for (int ni = 0; ni < 4; ni++)
            b[ni] = *(const short8*)&Bs[(wc * 64 + ni * 16 + l15) * 32 + quad * 8];
#pragma unroll
        for (int mi = 0; mi < 4; mi++)
#pragma unroll
            for (int ni = 0; ni < 4; ni++)
                acc[mi][ni] = __builtin_amdgcn_mfma_f32_16x16x32_bf16(a[mi], b[ni], acc[mi][ni], 0, 0, 0);
        __syncthreads();
    }
#pragma unroll
    for (int mi = 0; mi < 4; mi++)
#pragma unroll
        for (int ni = 0; ni < 4; ni++)
#pragma unroll
            for (int r = 0; r < 4; r++) {
                int row = m0 + wr * 64 + mi * 16 + quad * 4 + r;
                int col = n0 + wc * 64 + ni * 16 + l15;
                Cp[(size_t)blockIdx.z * zC + (size_t)row * N + col] = f2bf(acc[mi][ni][r]);
            }
}

// ---------------- fp8 fragment helpers (XOR half-swizzled LDS) ----------------
DEVFN int8v read_frag8(const unsigned char* buf, int rb, int quad) {
    int base = rb * 128;
    int h0 = (2 * quad) ^ (rb & 7);
    int h1 = (2 * quad + 1) ^ (rb & 7);
    int4v lo = *(const int4v*)&buf[base + h0 * 16];
    int4v hi = *(const int4v*)&buf[base + h1 * 16];
    return int8v{lo.x, lo.y, lo.z, lo.w, hi.x, hi.y, hi.z, hi.w};
}

// ---------------- fused gate+up GEMM, fp8 MX K=128: 128x64 tile of both ----------------
__global__ __launch_bounds__(256) void gateup_kernel(const unsigned char* __restrict__ A,
                                                     const unsigned char* __restrict__ Bg,
                                                     const unsigned char* __restrict__ Bu,
                                                     unsigned char* __restrict__ out) {
    __shared__ __align__(16) unsigned char As[128 * 128];
    __shared__ __align__(16) unsigned char Gs[64 * 128];
    __shared__ __align__(16) unsigned char Us[64 * 128];
    const int tid = threadIdx.x;
    const int lane = tid & 63, w = tid >> 6;
    const int quad = lane >> 4, l15 = lane & 15;
    const int wr = w >> 1, wc = w & 1;
    const int m0 = blockIdx.y * 128, n0 = blockIdx.x * 64;

    f32x4 aG[4][2], aU[4][2];
#pragma unroll
    for (int i = 0; i < 4; i++)
#pragma unroll
        for (int j = 0; j < 2; j++) { aG[i][j] = f32x4{0.f, 0.f, 0.f, 0.f}; aU[i][j] = f32x4{0.f, 0.f, 0.f, 0.f}; }

    const int lrow = lane >> 3;        // row within 8-row issue
    const int hA = (lane & 7) ^ lrow;  // swizzled half

    for (int kk = 0; kk < 1024; kk += 128) {
#pragma unroll
        for (int j = 0; j < 4; j++) {
            int i = w * 4 + j;                 // A: rows 8i..8i+7
            int r = i * 8 + lrow;
            load_lds16(A + (size_t)(m0 + r) * 1024 + kk + hA * 16, &As[i * 1024]);
        }
#pragma unroll
        for (int j = 0; j < 2; j++) {
            int i = w * 2 + j;                 // B: rows 8i..8i+7 (64 total)
            int r = i * 8 + lrow;
            load_lds16(Bg + (size_t)(n0 + r) * 1024 + kk + hA * 16, &Gs[i * 1024]);
            load_lds16(Bu + (size_t)(n0 + r) * 1024 + kk + hA * 16, &Us[i * 1024]);
        }
        __syncthreads();
        int8v a[4], bg[2], bu[2];
#pragma unroll
        for (int mi = 0; mi < 4; mi++)
            a[mi] = read_frag8(As, wr * 64 + mi * 16 + l15, quad);
#pragma unroll
        for (int ni = 0; ni < 2; ni++) {
            bg[ni] = read_frag8(Gs, wc * 32 + ni * 16 + l15, quad);
            bu[ni] = read_frag8(Us, wc * 32 + ni * 16 + l15, quad);
        }
#pragma unroll
        for (int mi = 0; mi < 4; mi++)
#pragma unroll
            for (int ni = 0; ni < 2; ni++) {
                aG[mi][ni] = mfma_fp8(a[mi], bg[ni], aG[mi][ni]);
                aU[mi][ni] = mfma_fp8(a[mi], bu[ni], aU[mi][ni]);
            }
        __syncthreads();
    }
#pragma unroll
    for (int mi = 0; mi < 4; mi++)
#pragma unroll
        for (int ni = 0; ni < 2; ni++)
#pragma unroll
            for (int r = 0; r < 4; r++) {
                int row = m0 + wr * 64 + mi * 16 + quad * 4 + r;
                int col = n0 + wc * 32 + ni * 16 + l15;
                float vg = aG[mi][ni][r] * (1.f / 64.f);
                float vu = aU[mi][ni][r] * (1.f / 64.f);
                float s = vg * fastrcp(1.f + __expf(-vg));
                out[(size_t)row * 4096 + col] = f2fp8(s * vu * 8.f);
            }
}

// ---------------- down GEMM, fp8 MX K=128, split-K=4, bf16 partials ----------------
__global__ __launch_bounds__(256) void down_gemm(const unsigned char* __restrict__ A,
                                                 const unsigned char* __restrict__ Bt,
                                                 unsigned short* __restrict__ Cp) {
    __shared__ __align__(16) unsigned char As[128 * 128];
    __shared__ __align__(16) unsigned char Bs[128 * 128];
    const int tid = threadIdx.x;
    const int lane = tid & 63, w = tid >> 6;
    const int quad = lane >> 4, l15 = lane & 15;
    const int wr = w >> 1, wc = w & 1;
    const int m0 = blockIdx.y * 128, n0 = blockIdx.x * 128;
    const int kbase = blockIdx.z * 1024;

    f32x4 acc[4][4];
#pragma unroll
    for (int i = 0; i < 4; i++)
#pragma unroll
        for (int j = 0; j < 4; j++) acc[i][j] = f32x4{0.f, 0.f, 0.f, 0.f};

    const int lrow = lane >> 3;
    const int hA = (lane & 7) ^ lrow;

    for (int kk = 0; kk < 1024; kk += 128) {
#pragma unroll
        for (int j = 0; j < 4; j++) {
            int i = w * 4 + j;
            int r = i * 8 + lrow;
            load_lds16(A + (size_t)(m0 + r) * 4096 + kbase + kk + hA * 16, &As[i * 1024]);
            load_lds16(Bt + (size_t)(n0 + r) * 4096 + kbase + kk + hA * 16, &Bs[i * 1024]);
        }
        __syncthreads();
        int8v a[4], b[4];
#pragma unroll
        for (int mi = 0; mi < 4; mi++)
            a[mi] = read_frag8(As, wr * 64 + mi * 16 + l15, quad);
#pragma unroll
        for (int ni = 0; ni < 4; ni++)
            b[ni] = read_frag8(Bs, wc * 64 + ni * 16 + l15, quad);
#pragma unroll
        for (int mi = 0; mi < 4; mi++)
#pragma unroll
            for (int ni = 0; ni < 4; ni++)
                acc[mi][ni] = mfma_fp8(a[mi], b[ni], acc[mi][ni]);
        __syncthreads();
    }
    const size_t Z = (size_t)NTOK * 1024;
#pragma unroll
    for (int mi = 0; mi < 4; mi++)
#pragma unroll
        for (int ni = 0; ni < 4; ni++)
#pragma unroll
            for (int r = 0; r < 4; r++) {
                int row = m0 + wr * 64 + mi * 16 + quad * 4 + r;
                int col = n0 + wc * 64 + ni * 16 + l15;
                Cp[(size_t)blockIdx.z * Z + (size_t)row * 1024 + col] =
                    f2bf(acc[mi][ni][r] * (1.f / 128.f));
            }
}

// ---------------- out-proj reduce: x2 = sum(p[0..3]) + x; xn2 = fp8(rms*4); init outk ----------------
__global__ __launch_bounds__(256) void reduce_out(const unsigned short* __restrict__ p,
                                                  const float* __restrict__ x,
                                                  const float* __restrict__ scale,
                                                  float* __restrict__ x2,
                                                  unsigned char* __restrict__ xn2,
                                                  const float* __restrict__ ksum,
                                                  float* __restrict__ outk) {
    __shared__ float red[4];
    int row = blockIdx.x, tid = threadIdx.x;
    if (row == 0 && tid == 0) outk[0] = ksum[0];
    size_t base = (size_t)row * 1024 + tid * 4;
    const size_t Z = (size_t)NTOK * 1024;
    float4 v = *(const float4*)&x[base];
#pragma unroll
    for (int z = 0; z < 4; z++) {
        ushort4 u = *(const ushort4*)&p[base + z * Z];
        v.x += bf2f(u.x); v.y += bf2f(u.y); v.z += bf2f(u.z); v.w += bf2f(u.w);
    }
    *(float4*)&x2[base] = v;
    float ss = v.x * v.x + v.y * v.y + v.z * v.z + v.w * v.w;
#pragma unroll
    for (int m = 32; m; m >>= 1) ss += __shfl_xor(ss, m, 64);
    if ((tid & 63) == 0) red[tid >> 6] = ss;
    __syncthreads();
    float tot = red[0] + red[1] + red[2] + red[3];
    float inv = rsqrtf(tot * (1.f / 1024.f) + 1e-6f) * 4.f;   // x4 fp8 prescale
    const float4 sc = *(const float4*)&scale[tid * 4];
    xn2[base + 0] = f2fp8(v.x * inv * (1.f + sc.x));
    xn2[base + 1] = f2fp8(v.y * inv * (1.f + sc.y));
    xn2[base + 2] = f2fp8(v.z * inv * (1.f + sc.z));
    xn2[base + 3] = f2fp8(v.w * inv * (1.f + sc.w));
}

// ---------------- down reduce: out = sum(p[0..3]) + x2, fused kurtosis ----------------
__global__ __launch_bounds__(256) void reduce_down(const unsigned short* __restrict__ p,
                                                   const float* __restrict__ x2,
                                                   float* __restrict__ outx,
                                                   float* __restrict__ outk) {
    __shared__ float red[4], r2[4], r4[4];
    int row = blockIdx.x, tid = threadIdx.x;
    size_t base = (size_t)row * 1024 + tid * 4;
    const size_t Z = (size_t)NTOK * 1024;
    float4 v = *(const float4*)&x2[base];
#pragma unroll
    for (int z = 0; z < 4; z++) {
        ushort4 u = *(const ushort4*)&p[base + z * Z];
        v.x += bf2f(u.x); v.y += bf2f(u.y); v.z += bf2f(u.z); v.w += bf2f(u.w);
    }
    *(float4*)&outx[base] = v;
    float s = v.x + v.y + v.z + v.w;
#pragma unroll
    for (int m = 32; m; m >>= 1) s += __shfl_xor(s, m, 64);
    if ((tid & 63) == 0) red[tid >> 6] = s;
    __syncthreads();
    float mean = (red[0] + red[1] + red[2] + red[3]) * (1.f / 1024.f);
    float cx = v.x - mean, cy = v.y - mean, cz = v.z - mean, cw = v.w - mean;
    float x2v = cx * cx, y2 = cy * cy, z2 = cz * cz, w2 = cw * cw;
    float c2 = x2v + y2 + z2 + w2;
    float c4 = x2v * x2v + y2 * y2 + z2 * z2 + w2 * w2;
#pragma unroll
    for (int m = 32; m; m >>= 1) {
        c2 += __shfl_xor(c2, m, 64);
        c4 += __shfl_xor(c4, m, 64);
    }
    if ((tid & 63) == 0) { r2[tid >> 6] = c2; r4[tid >> 6] = c4; }
    __syncthreads();
    if (tid == 0) {
        float m2 = (r2[0] + r2[1] + r2[2] + r2[3]) * (1.f / 1024.f);
        float m4 = (r4[0] + r4[1] + r4[2] + r4[3]) * (1.f / 1024.f);
        float kurt = m4 / (m2 * m2 + 1e-6f) - 3.f;
        if (kurt > 0.f) atomicAdd(outk, kurt);
    }
}

// ---------------- ropevt: reduce qkv split-K partials + RoPE scatter + V transpose ----------------
__global__ __launch_bounds__(256) void ropevt_kernel(const unsigned short* __restrict__ qkvp,
                                                     unsigned short* __restrict__ qb,
                                                     unsigned short* __restrict__ kb,
                                                     unsigned short* __restrict__ vt) {
    __shared__ float sv[32], cv[32];
    __shared__ unsigned short tile[64][68];
    const size_t Z = (size_t)NTOK * 2048;
    int id = blockIdx.x;
    int tid = threadIdx.x;
    if (id < NTOK) {
        int tok = id;
        int b = tok >> 11, t = tok & 2047;
        if (tid < 32) {
            float fr = (float)tid * (1.f / 32.f);
            float freq = powf(1e6f, -fr);
            float a = (float)t * freq;
            sv[tid] = sinf(a);
            cv[tid] = cosf(a);
        }
        __syncthreads();
        const unsigned short* r0 = qkvp + (size_t)tok * 2048;
        const unsigned short* r1 = r0 + Z;
#pragma unroll
        for (int e = tid; e < 1536; e += 256) {
            int u = e >> 6, d = e & 63;
            int col = (u < 16) ? (u * 64 + d) : (1024 + (u - 16) * 64 + d);
            int pcol = (d < 32) ? col + 32 : col - 32;
            float sgn = (d < 32) ? -1.f : 1.f;
            float vc = bf2f(r0[col]) + bf2f(r1[col]);
            float vp = bf2f(r0[pcol]) + bf2f(r1[pcol]);
            float o = vc * cv[d & 31] + sgn * vp * sv[d & 31];
            if (u < 16)
                qb[((size_t)(b * 16 + u) * 2048 + t) * 64 + d] = f2bf(o);
            else
                kb[((size_t)(b * 8 + (u - 16)) * 2048 + t) * 64 + d] = f2bf(o);
        }
    } else {
        int lid = id - NTOK;
        int b = lid >> 8, h = (lid >> 5) & 7, t0 = (lid & 31) * 64;
        int d = tid & 63, tr = tid >> 6;
#pragma unroll
        for (int i = 0; i < 16; i++) {
            int t = tr + i * 4;
            size_t gi = (size_t)(b * 2048 + t0 + t) * 2048 + 1536 + h * 64 + d;
            tile[t][d] = f2bf(bf2f(qkvp[gi]) + bf2f(qkvp[gi + Z]));
        }
        __syncthreads();
        int tt = tid & 63, dr = tid >> 6;
#pragma unroll
        for (int i = 0; i < 16; i++) {
            int dd = dr + i * 4;
            vt[((size_t)(b * 8 + h) * 64 + dd) * 2048 + t0 + tt] = tile[tt][dd];
        }
    }
}

// ---------------- flash attention: 64-key steps, dbuf P, rcp math, ones-MFMA row sums ----------------
__global__ __launch_bounds__(256) void attn_kernel(const unsigned short* __restrict__ qb,
                                                   const unsigned short* __restrict__ kb,
                                                   const unsigned short* __restrict__ vt,
                                                   unsigned short* __restrict__ ctx) {
    __shared__ __align__(16) unsigned short P[4][2][16 * 64];
    const int tid = threadIdx.x, lane = tid & 63, w = tid >> 6;
    const int quad = lane >> 4, l15 = lane & 15;
    const int qt = blockIdx.x, H = blockIdx.y, b = blockIdx.z;
    const int hkv = H & 7;
    const int qw = qt * 64 + w * 16;

    const unsigned short* qbase = qb + ((size_t)(b * 16 + H) * 2048 + qw) * 64;
    short8 aq0 = *(const short8*)(qbase + (size_t)l15 * 64 + quad * 8);
    short8 aq1 = *(const short8*)(qbase + (size_t)l15 * 64 + 32 + quad * 8);

    const unsigned short* kbase = kb + (size_t)(b * 8 + hkv) * 2048 * 64;
    const unsigned short* vbase = vt + (size_t)(b * 8 + hkv) * 64 * 2048;

    const short bf1 = (short)0x3F80;   // bf16 1.0
    const short8 ones = {bf1, bf1, bf1, bf1, bf1, bf1, bf1, bf1};

    f32x4 O[4];
#pragma unroll
    for (int i = 0; i < 4; i++) O[i] = f32x4{0.f, 0.f, 0.f, 0.f};
    f32x4 lacc = f32x4{0.f, 0.f, 0.f, 0.f};

    int kstart = qw - 511;
    if (kstart < 0) kstart = 0;
    kstart &= ~63;
    int buf = 0;

    for (int k0 = kstart; k0 <= qw + 15; k0 += 64) {
        f32x4 S[4];
#pragma unroll
        for (int c = 0; c < 4; c++) {
            const unsigned short* kp = kbase + (size_t)(k0 + c * 16 + l15) * 64 + quad * 8;
            short8 kf0 = *(const short8*)kp;
            short8 kf1 = *(const short8*)(kp + 32);
            f32x4 s = __builtin_amdgcn_mfma_f32_16x16x32_bf16(aq0, kf0, f32x4{0.f, 0.f, 0.f, 0.f}, 0, 0, 0);
            s = __builtin_amdgcn_mfma_f32_16x16x32_bf16(aq1, kf1, s, 0, 0, 0);
            S[c] = s;
        }
        unsigned short* Pw = P[w][buf];
#pragma unroll
        for (int c = 0; c < 4; c++)
#pragma unroll
            for (int r = 0; r < 4; r++) {
                int i = qw + quad * 4 + r;
                int j = k0 + c * 16 + l15;
                // p = exp(50*tanh(S*0.0025)); tanh via exp + rcp
                float Sc = fminf(3200.f, fmaxf(-3200.f, S[c][r]));
                float e = __expf(Sc * 0.005f);
                float y = 50.f - 100.f * fastrcp(e + 1.f);
                bool ok = (j <= i) && ((i - j) < 512);
                float pv = ok ? __expf(y) : 0.f;
                Pw[(quad * 4 + r) * 64 + c * 16 + l15] = f2bf(pv);
            }
        asm volatile("s_waitcnt lgkmcnt(0)" ::: "memory");
        short8 pf0 = *(const short8*)&Pw[l15 * 64 + quad * 8];
        short8 pf1 = *(const short8*)&Pw[l15 * 64 + 32 + quad * 8];
#pragma unroll
        for (int ni = 0; ni < 4; ni++) {
            const unsigned short* vp = vbase + (size_t)(ni * 16 + l15) * 2048 + k0;
            short8 vf0 = *(const short8*)(vp + quad * 8);
            short8 vf1 = *(const short8*)(vp + 32 + quad * 8);
            O[ni] = __builtin_amdgcn_mfma_f32_16x16x32_bf16(pf0, vf0, O[ni], 0, 0, 0);
            O[ni] = __builtin_amdgcn_mfma_f32_16x16x32_bf16(pf1, vf1, O[ni], 0, 0, 0);
        }
        lacc = __builtin_amdgcn_mfma_f32_16x16x32_bf16(pf0, ones, lacc, 0, 0, 0);
        lacc = __builtin_amdgcn_mfma_f32_16x16x32_bf16(pf1, ones, lacc, 0, 0, 0);
        buf ^= 1;
    }
#pragma unroll
    for (int r = 0; r < 4; r++) {
        float inv = fastrcp(lacc[r]);
        int i = qw + quad * 4 + r;
        size_t tok = (size_t)b * 2048 + i;
#pragma unroll
        for (int ni = 0; ni < 4; ni++)
            ctx[tok * 1024 + H * 64 + ni * 16 + l15] = f2bf(O[ni][r] * inv);
    }
}

// ---------------- launch ----------------
extern "C" void kernel_launch(void* const* d_in, const int* in_sizes, int n_in,
                              void* d_out, int out_size, void* d_ws, size_t ws_size,
                              hipStream_t stream) {
    const float* x = (const float*)d_in[0];
    const float* ksum = (const float*)d_in[1];
    const float* rms1_scale = (const float*)d_in[2];
    const float* q_w = (const float*)d_in[3];
    const float* k_w = (const float*)d_in[4];
    const float* v_w = (const float*)d_in[5];
    const float* out_w = (const float*)d_in[6];
    const float* rms2_scale = (const float*)d_in[7];
    const float* gate_w = (const float*)d_in[8];
    const float* up_w = (const float*)d_in[9];
    const float* down_w = (const float*)d_in[10];

    char* ws = (char*)d_ws;
    unsigned short* wqkv = (unsigned short*)(ws + OFF_WQKV);
    unsigned short* wout = (unsigned short*)(ws + OFF_WOUT);
    unsigned char* wgate = (unsigned char*)(ws + OFF_WGATE);
    unsigned char* wup = (unsigned char*)(ws + OFF_WUP);
    unsigned char* wdown = (unsigned char*)(ws + OFF_WDOWN);
    unsigned short* xn1 = (unsigned short*)(ws + OFF_XN1);
    unsigned short* qkvp = (unsigned short*)(ws + OFF_QKVP);
    unsigned short* p2 = (unsigned short*)(ws + OFF_P2);
    unsigned short* qb = (unsigned short*)(ws + OFF_QB);
    unsigned short* kb = (unsigned short*)(ws + OFF_KB);
    unsigned short* vtb = (unsigned short*)(ws + OFF_VT);
    unsigned short* ctx = (unsigned short*)(ws + OFF_CTX);
    float* x2 = (float*)(ws + OFF_X2);
    unsigned char* xn2 = (unsigned char*)(ws + OFF_XN2);
    unsigned char* g = (unsigned char*)(ws + OFF_G);
    unsigned short* p4 = (unsigned short*)(ws + OFF_P4);
    float* outx = (float*)d_out;
    float* outk = outx + (size_t)NTOK * C;

    // prep: weight transpose+cast (bf16 qkv/out, fp8 x16 mlp) + rms1
    prep_kernel<<<15360 + NTOK, 256, 0, stream>>>(
        q_w, k_w, v_w, out_w, gate_w, up_w, down_w,
        wqkv, wout, wgate, wup, wdown, x, rms1_scale, xn1);

    // QKV projection, split-K=2 -> bf16 partials 2x[4096][2048]
    gemm128<<<dim3(2048 / 128, NTOK / 128, 2), 256, 0, stream>>>(
        xn1, wqkv, qkvp, 2048, 512, 1024, 1024, 512, 512, (size_t)NTOK * 2048);

    // partial-sum + RoPE scatter + V transpose
    ropevt_kernel<<<NTOK + 512, 256, 0, stream>>>(qkvp, qb, kb, vtb);

    // attention
    attn_kernel<<<dim3(T / 64, NH, Bsz), 256, 0, stream>>>(qb, kb, vtb, ctx);

    // out projection, split-K=4 bf16 partials, then fused residual+rms2(fp8 x4)+kurt init
    gemm128<<<dim3(1024 / 128, NTOK / 128, 4), 256, 0, stream>>>(
        ctx, wout, p2, 1024, 256, 1024, 1024, 256, 256, (size_t)NTOK * 1024);
    reduce_out<<<NTOK, 256, 0, stream>>>(p2, x, rms2_scale, x2, xn2, ksum, outk);

    // fused gate+up fp8 MX -> g = fp8(silu(gate)*up * 8)
    gateup_kernel<<<dim3(HID / 64, NTOK / 128), 256, 0, stream>>>(xn2, wgate, wup, g);

    // down projection fp8 MX, split-K=4 bf16 partials, then fused residual+kurtosis
    down_gemm<<<dim3(1024 / 128, NTOK / 128, 4), 256, 0, stream>>>(g, wdown, p4);
    reduce_down<<<NTOK, 256, 0, stream>>>(p4, x2, outx, outk);

    (void)in_sizes; (void)n_in; (void)out_size; (void)ws_size;
}

// Round 9
// 343.348 us; speedup vs baseline: 1.5280x; 1.1048x over previous
//
#include <hip/hip_runtime.h>
#include <hip/hip_bf16.h>

typedef __attribute__((ext_vector_type(8))) short short8;
typedef __attribute__((ext_vector_type(4))) float f32x4;
typedef __attribute__((ext_vector_type(4))) int int4v;
typedef __attribute__((ext_vector_type(8))) int int8v;

#define DEVFN static __device__ __forceinline__

DEVFN float bf2f(unsigned short u) {
    unsigned int i = ((unsigned int)u) << 16;
    float f; __builtin_memcpy(&f, &i, 4); return f;
}
DEVFN unsigned short f2bf(float f) {
    unsigned int i; __builtin_memcpy(&i, &f, 4);
    unsigned int r = i + 0x7fffu + ((i >> 16) & 1u);
    return (unsigned short)(r >> 16);
}
DEVFN unsigned char f2fp8(float f) {
    int r = __builtin_amdgcn_cvt_pk_fp8_f32(f, f, 0, false);
    return (unsigned char)(r & 0xff);
}
DEVFN float fastrcp(float x) { return __builtin_amdgcn_rcpf(x); }

DEVFN void load_lds16(const void* g, void* l) {
    __builtin_amdgcn_global_load_lds(
        (__attribute__((address_space(1))) void*)g,
        (__attribute__((address_space(3))) void*)l, 16, 0, 0);
}

DEVFN f32x4 mfma_fp8(int8v a, int8v b, f32x4 c) {
    // cbsz=0 (A=fp8 e4m3), blgp=0 (B=fp8 e4m3), scales = 1.0 (e8m0 127)
    return __builtin_amdgcn_mfma_scale_f32_16x16x128_f8f6f4(
        a, b, c, 0, 0, 0, 0x7F7F7F7F, 0, 0x7F7F7F7F);
}

// ---------------- constants ----------------
constexpr int Bsz = 2, T = 2048, C = 1024;
constexpr int NH = 16, NKV = 8, HD = 64;
constexpr int HID = 4096;
constexpr int NTOK = Bsz * T;              // 4096
constexpr size_t MiB = 1024 * 1024;

// workspace offsets (bytes)
constexpr size_t OFF_WQKV = 0;             // bf16 [2048][1024]   4 MiB
constexpr size_t OFF_WOUT = 4 * MiB;       // bf16 [1024][1024]   2 MiB
constexpr size_t OFF_WGATE = 6 * MiB;      // fp8  [4096][1024]   4 MiB (x16)
constexpr size_t OFF_WUP = 10 * MiB;       // fp8  [4096][1024]   4 MiB (x16)
constexpr size_t OFF_WDOWN = 14 * MiB;     // fp8  [1024][4096]   4 MiB (x16)
constexpr size_t OFF_XN1 = 18 * MiB;       // bf16 [4096][1024]   8 MiB
constexpr size_t OFF_QKVP = 26 * MiB;      // bf16 2x[4096][2048] 32 MiB (dead after ropevt)
constexpr size_t OFF_P2 = 26 * MiB;        // bf16 4x[4096][1024] 32 MiB (reuses QKVP)
constexpr size_t OFF_QB = 58 * MiB;        // bf16 [2][16][2048][64] 8 MiB
constexpr size_t OFF_KB = 66 * MiB;        // bf16 [2][8][2048][64]  4 MiB
constexpr size_t OFF_VT = 70 * MiB;        // bf16 [2][8][64][2048]  4 MiB
constexpr size_t OFF_CTX = 74 * MiB;       // bf16 [4096][1024]   8 MiB
constexpr size_t OFF_X2 = 82 * MiB;        // f32  [4096][1024]  16 MiB
constexpr size_t OFF_XN2 = 98 * MiB;       // fp8  [4096][1024]   4 MiB (x4)
constexpr size_t OFF_G = 102 * MiB;        // fp8  [4096][4096]  16 MiB (x8)
constexpr size_t OFF_P4 = 118 * MiB;       // bf16 4x[4096][1024] 32 MiB
// total 150 MiB

// ---------------- prep: weight cast+transpose (7 mats) + rms1, one launch ----------------
// blocks [0,15360): transpose 32x32 tiles; [15360,19456): rms rows
__global__ __launch_bounds__(256) void prep_kernel(
    const float* __restrict__ qk, const float* __restrict__ kk2,
    const float* __restrict__ vk, const float* __restrict__ ok,
    const float* __restrict__ gk, const float* __restrict__ uk,
    const float* __restrict__ dk,
    unsigned short* __restrict__ wqkv, unsigned short* __restrict__ wout,
    unsigned char* __restrict__ wgate, unsigned char* __restrict__ wup,
    unsigned char* __restrict__ wdown,
    const float* __restrict__ x, const float* __restrict__ rms1_scale,
    unsigned short* __restrict__ xn1) {
    __shared__ float t[32][33];
    __shared__ float red[4];
    int id = blockIdx.x;
    int tid = threadIdx.x;
    if (id >= 15360) {
        int row = id - 15360;
        const float4 v = *(const float4*)&x[(size_t)row * 1024 + tid * 4];
        float ss = v.x * v.x + v.y * v.y + v.z * v.z + v.w * v.w;
#pragma unroll
        for (int m = 32; m; m >>= 1) ss += __shfl_xor(ss, m, 64);
        if ((tid & 63) == 0) red[tid >> 6] = ss;
        __syncthreads();
        float tot = red[0] + red[1] + red[2] + red[3];
        float inv = rsqrtf(tot * (1.f / 1024.f) + 1e-6f);
        const float4 sc = *(const float4*)&rms1_scale[tid * 4];
        size_t o = (size_t)row * 1024 + tid * 4;
        xn1[o + 0] = f2bf(v.x * inv * (1.f + sc.x));
        xn1[o + 1] = f2bf(v.y * inv * (1.f + sc.y));
        xn1[o + 2] = f2bf(v.z * inv * (1.f + sc.z));
        xn1[o + 3] = f2bf(v.w * inv * (1.f + sc.w));
        return;
    }
    const float* in; int K, N, nx, base; int fp8 = 0;
    unsigned short* out16 = nullptr; unsigned char* out8 = nullptr;
    if (id < 1024)       { in = qk;  out16 = wqkv;                       K = 1024; N = 1024; nx = 32;  base = 0; }
    else if (id < 1536)  { in = kk2; out16 = wqkv + (size_t)1024 * 1024; K = 1024; N = 512;  nx = 16;  base = 1024; }
    else if (id < 2048)  { in = vk;  out16 = wqkv + (size_t)1536 * 1024; K = 1024; N = 512;  nx = 16;  base = 1536; }
    else if (id < 3072)  { in = ok;  out16 = wout;                       K = 1024; N = 1024; nx = 32;  base = 2048; }
    else if (id < 7168)  { in = gk;  out8 = wgate; fp8 = 1;              K = 1024; N = 4096; nx = 128; base = 3072; }
    else if (id < 11264) { in = uk;  out8 = wup; fp8 = 1;                K = 1024; N = 4096; nx = 128; base = 7168; }
    else                 { in = dk;  out8 = wdown; fp8 = 1;              K = 4096; N = 1024; nx = 32;  base = 11264; }
    int lid = id - base;
    int n0 = (lid % nx) * 32, k0 = (lid / nx) * 32;
    int tx = tid & 31, ty = tid >> 5;
#pragma unroll
    for (int i = 0; i < 4; i++)
        t[ty + 8 * i][tx] = in[(size_t)(k0 + ty + 8 * i) * N + n0 + tx];
    __syncthreads();
    if (fp8) {
#pragma unroll
        for (int i = 0; i < 4; i++)
            out8[(size_t)(n0 + ty + 8 * i) * K + k0 + tx] = f2fp8(t[tx][ty + 8 * i] * 16.f);
    } else {
#pragma unroll
        for (int i = 0; i < 4; i++)
            out16[(size_t)(n0 + ty + 8 * i) * K + k0 + tx] = f2bf(t[tx][ty + 8 * i]);
    }
}

// ---------------- bf16 GEMM (qkv, out-proj): C = A @ Bt^T ----------------
__global__ __launch_bounds__(256) void gemm128(const unsigned short* __restrict__ A,
                                               const unsigned short* __restrict__ Bt,
                                               unsigned short* __restrict__ Cp,
                                               int N, int K, int lda, int ldb,
                                               size_t zA, size_t zB, size_t zC) {
    __shared__ __align__(16) unsigned short As[128 * 32];
    __shared__ __align__(16) unsigned short Bs[128 * 32];
    A += (size_t)blockIdx.z * zA;
    Bt += (size_t)blockIdx.z * zB;
    const int tid = threadIdx.x;
    const int lane = tid & 63, w = tid >> 6;
    const int quad = lane >> 4, l15 = lane & 15;
    const int wr = w >> 1, wc = w & 1;
    const int m0 = blockIdx.y * 128, n0 = blockIdx.x * 128;

    f32x4 acc[4][4];
#pragma unroll
    for (int i = 0; i < 4; i++)
#pragma unroll
        for (int j = 0; j < 4; j++) acc[i][j] = f32x4{0.f, 0.f, 0.f, 0.f};

    const int stRow = (w << 4) + (lane >> 2);
    const int stCol = (lane & 3) << 3;

    for (int kk = 0; kk < K; kk += 32) {
#pragma unroll
        for (int i = 0; i < 2; i++) {
            load_lds16(A + (size_t)(m0 + (i << 6) + stRow) * lda + kk + stCol,
                       &As[((i << 6) + (w << 4)) * 32]);
            load_lds16(Bt + (size_t)(n0 + (i << 6) + stRow) * ldb + kk + stCol,
                       &Bs[((i << 6) + (w << 4)) * 32]);
        }
        __syncthreads();
        short8 a[4], b[4];
#pragma unroll
        for (int mi = 0; mi < 4; mi++)
            a[mi] = *(const short8*)&As[(wr * 64 + mi * 16 + l15) * 32 + quad * 8];
#pragma unroll
        for (int ni = 0; ni < 4; ni++)
            b[ni] = *(const short8*)&Bs[(wc * 64 + ni * 16 + l15) * 32 + quad * 8];
#pragma unroll
        for (int mi = 0; mi < 4; mi++)
#pragma unroll
            for (int ni = 0; ni < 4; ni++)
                acc[mi][ni] = __builtin_amdgcn_mfma_f32_16x16x32_bf16(a[mi], b[ni], acc[mi][ni], 0, 0, 0);
        __syncthreads();
    }
#pragma unroll
    for (int mi = 0; mi < 4; mi++)
#pragma unroll
        for (int ni = 0; ni < 4; ni++)
#pragma unroll
            for (int r = 0; r < 4; r++) {
                int row = m0 + wr * 64 + mi * 16 + quad * 4 + r;
                int col = n0 + wc * 64 + ni * 16 + l15;
                Cp[(size_t)blockIdx.z * zC + (size_t)row * N + col] = f2bf(acc[mi][ni][r]);
            }
}

// ---------------- fp8 fragment helpers (XOR half-swizzled LDS) ----------------
DEVFN int8v read_frag8(const unsigned char* buf, int rb, int quad) {
    int base = rb * 128;
    int h0 = (2 * quad) ^ (rb & 7);
    int h1 = (2 * quad + 1) ^ (rb & 7);
    int4v lo = *(const int4v*)&buf[base + h0 * 16];
    int4v hi = *(const int4v*)&buf[base + h1 * 16];
    return int8v{lo.x, lo.y, lo.z, lo.w, hi.x, hi.y, hi.z, hi.w};
}

// ---------------- fused gate+up GEMM, fp8 MX K=128: 128x64 tile of both ----------------
__global__ __launch_bounds__(256) void gateup_kernel(const unsigned char* __restrict__ A,
                                                     const unsigned char* __restrict__ Bg,
                                                     const unsigned char* __restrict__ Bu,
                                                     unsigned char* __restrict__ out) {
    __shared__ __align__(16) unsigned char As[128 * 128];
    __shared__ __align__(16) unsigned char Gs[64 * 128];
    __shared__ __align__(16) unsigned char Us[64 * 128];
    const int tid = threadIdx.x;
    const int lane = tid & 63, w = tid >> 6;
    const int quad = lane >> 4, l15 = lane & 15;
    const int wr = w >> 1, wc = w & 1;
    const int m0 = blockIdx.y * 128, n0 = blockIdx.x * 64;

    f32x4 aG[4][2], aU[4][2];
#pragma unroll
    for (int i = 0; i < 4; i++)
#pragma unroll
        for (int j = 0; j < 2; j++) { aG[i][j] = f32x4{0.f, 0.f, 0.f, 0.f}; aU[i][j] = f32x4{0.f, 0.f, 0.f, 0.f}; }

    const int lrow = lane >> 3;        // row within 8-row issue
    const int hA = (lane & 7) ^ lrow;  // swizzled half

    for (int kk = 0; kk < 1024; kk += 128) {
#pragma unroll
        for (int j = 0; j < 4; j++) {
            int i = w * 4 + j;                 // A: rows 8i..8i+7
            int r = i * 8 + lrow;
            load_lds16(A + (size_t)(m0 + r) * 1024 + kk + hA * 16, &As[i * 1024]);
        }
#pragma unroll
        for (int j = 0; j < 2; j++) {
            int i = w * 2 + j;                 // B: rows 8i..8i+7 (64 total)
            int r = i * 8 + lrow;
            load_lds16(Bg + (size_t)(n0 + r) * 1024 + kk + hA * 16, &Gs[i * 1024]);
            load_lds16(Bu + (size_t)(n0 + r) * 1024 + kk + hA * 16, &Us[i * 1024]);
        }
        __syncthreads();
        int8v a[4], bg[2], bu[2];
#pragma unroll
        for (int mi = 0; mi < 4; mi++)
            a[mi] = read_frag8(As, wr * 64 + mi * 16 + l15, quad);
#pragma unroll
        for (int ni = 0; ni < 2; ni++) {
            bg[ni] = read_frag8(Gs, wc * 32 + ni * 16 + l15, quad);
            bu[ni] = read_frag8(Us, wc * 32 + ni * 16 + l15, quad);
        }
#pragma unroll
        for (int mi = 0; mi < 4; mi++)
#pragma unroll
            for (int ni = 0; ni < 2; ni++) {
                aG[mi][ni] = mfma_fp8(a[mi], bg[ni], aG[mi][ni]);
                aU[mi][ni] = mfma_fp8(a[mi], bu[ni], aU[mi][ni]);
            }
        __syncthreads();
    }
#pragma unroll
    for (int mi = 0; mi < 4; mi++)
#pragma unroll
        for (int ni = 0; ni < 2; ni++)
#pragma unroll
            for (int r = 0; r < 4; r++) {
                int row = m0 + wr * 64 + mi * 16 + quad * 4 + r;
                int col = n0 + wc * 32 + ni * 16 + l15;
                float vg = aG[mi][ni][r] * (1.f / 64.f);
                float vu = aU[mi][ni][r] * (1.f / 64.f);
                float s = vg * fastrcp(1.f + __expf(-vg));
                out[(size_t)row * 4096 + col] = f2fp8(s * vu * 8.f);
            }
}

// ---------------- down GEMM, fp8 MX K=128, split-K=4, bf16 partials ----------------
__global__ __launch_bounds__(256) void down_gemm(const unsigned char* __restrict__ A,
                                                 const unsigned char* __restrict__ Bt,
                                                 unsigned short* __restrict__ Cp) {
    __shared__ __align__(16) unsigned char As[128 * 128];
    __shared__ __align__(16) unsigned char Bs[128 * 128];
    const int tid = threadIdx.x;
    const int lane = tid & 63, w = tid >> 6;
    const int quad = lane >> 4, l15 = lane & 15;
    const int wr = w >> 1, wc = w & 1;
    const int m0 = blockIdx.y * 128, n0 = blockIdx.x * 128;
    const int kbase = blockIdx.z * 1024;

    f32x4 acc[4][4];
#pragma unroll
    for (int i = 0; i < 4; i++)
#pragma unroll
        for (int j = 0; j < 4; j++) acc[i][j] = f32x4{0.f, 0.f, 0.f, 0.f};

    const int lrow = lane >> 3;
    const int hA = (lane & 7) ^ lrow;

    for (int kk = 0; kk < 1024; kk += 128) {
#pragma unroll
        for (int j = 0; j < 4; j++) {
            int i = w * 4 + j;
            int r = i * 8 + lrow;
            load_lds16(A + (size_t)(m0 + r) * 4096 + kbase + kk + hA * 16, &As[i * 1024]);
            load_lds16(Bt + (size_t)(n0 + r) * 4096 + kbase + kk + hA * 16, &Bs[i * 1024]);
        }
        __syncthreads();
        int8v a[4], b[4];
#pragma unroll
        for (int mi = 0; mi < 4; mi++)
            a[mi] = read_frag8(As, wr * 64 + mi * 16 + l15, quad);
#pragma unroll
        for (int ni = 0; ni < 4; ni++)
            b[ni] = read_frag8(Bs, wc * 64 + ni * 16 + l15, quad);
#pragma unroll
        for (int mi = 0; mi < 4; mi++)
#pragma unroll
            for (int ni = 0; ni < 4; ni++)
                acc[mi][ni] = mfma_fp8(a[mi], b[ni], acc[mi][ni]);
        __syncthreads();
    }
    const size_t Z = (size_t)NTOK * 1024;
#pragma unroll
    for (int mi = 0; mi < 4; mi++)
#pragma unroll
        for (int ni = 0; ni < 4; ni++)
#pragma unroll
            for (int r = 0; r < 4; r++) {
                int row = m0 + wr * 64 + mi * 16 + quad * 4 + r;
                int col = n0 + wc * 64 + ni * 16 + l15;
                Cp[(size_t)blockIdx.z * Z + (size_t)row * 1024 + col] =
                    f2bf(acc[mi][ni][r] * (1.f / 128.f));
            }
}

// ---------------- out-proj reduce: x2 = sum(p[0..3]) + x; xn2 = fp8(rms*4); init outk ----------------
__global__ __launch_bounds__(256) void reduce_out(const unsigned short* __restrict__ p,
                                                  const float* __restrict__ x,
                                                  const float* __restrict__ scale,
                                                  float* __restrict__ x2,
                                                  unsigned char* __restrict__ xn2,
                                                  const float* __restrict__ ksum,
                                                  float* __restrict__ outk) {
    __shared__ float red[4];
    int row = blockIdx.x, tid = threadIdx.x;
    if (row == 0 && tid == 0) outk[0] = ksum[0];
    size_t base = (size_t)row * 1024 + tid * 4;
    const size_t Z = (size_t)NTOK * 1024;
    float4 v = *(const float4*)&x[base];
#pragma unroll
    for (int z = 0; z < 4; z++) {
        ushort4 u = *(const ushort4*)&p[base + z * Z];
        v.x += bf2f(u.x); v.y += bf2f(u.y); v.z += bf2f(u.z); v.w += bf2f(u.w);
    }
    *(float4*)&x2[base] = v;
    float ss = v.x * v.x + v.y * v.y + v.z * v.z + v.w * v.w;
#pragma unroll
    for (int m = 32; m; m >>= 1) ss += __shfl_xor(ss, m, 64);
    if ((tid & 63) == 0) red[tid >> 6] = ss;
    __syncthreads();
    float tot = red[0] + red[1] + red[2] + red[3];
    float inv = rsqrtf(tot * (1.f / 1024.f) + 1e-6f) * 4.f;   // x4 fp8 prescale
    const float4 sc = *(const float4*)&scale[tid * 4];
    xn2[base + 0] = f2fp8(v.x * inv * (1.f + sc.x));
    xn2[base + 1] = f2fp8(v.y * inv * (1.f + sc.y));
    xn2[base + 2] = f2fp8(v.z * inv * (1.f + sc.z));
    xn2[base + 3] = f2fp8(v.w * inv * (1.f + sc.w));
}

// ---------------- down reduce: out = sum(p[0..3]) + x2, fused kurtosis ----------------
__global__ __launch_bounds__(256) void reduce_down(const unsigned short* __restrict__ p,
                                                   const float* __restrict__ x2,
                                                   float* __restrict__ outx,
                                                   float* __restrict__ outk) {
    __shared__ float red[4], r2[4], r4[4];
    int row = blockIdx.x, tid = threadIdx.x;
    size_t base = (size_t)row * 1024 + tid * 4;
    const size_t Z = (size_t)NTOK * 1024;
    float4 v = *(const float4*)&x2[base];
#pragma unroll
    for (int z = 0; z < 4; z++) {
        ushort4 u = *(const ushort4*)&p[base + z * Z];
        v.x += bf2f(u.x); v.y += bf2f(u.y); v.z += bf2f(u.z); v.w += bf2f(u.w);
    }
    *(float4*)&outx[base] = v;
    float s = v.x + v.y + v.z + v.w;
#pragma unroll
    for (int m = 32; m; m >>= 1) s += __shfl_xor(s, m, 64);
    if ((tid & 63) == 0) red[tid >> 6] = s;
    __syncthreads();
    float mean = (red[0] + red[1] + red[2] + red[3]) * (1.f / 1024.f);
    float cx = v.x - mean, cy = v.y - mean, cz = v.z - mean, cw = v.w - mean;
    float x2v = cx * cx, y2 = cy * cy, z2 = cz * cz, w2 = cw * cw;
    float c2 = x2v + y2 + z2 + w2;
    float c4 = x2v * x2v + y2 * y2 + z2 * z2 + w2 * w2;
#pragma unroll
    for (int m = 32; m; m >>= 1) {
        c2 += __shfl_xor(c2, m, 64);
        c4 += __shfl_xor(c4, m, 64);
    }
    if ((tid & 63) == 0) { r2[tid >> 6] = c2; r4[tid >> 6] = c4; }
    __syncthreads();
    if (tid == 0) {
        float m2 = (r2[0] + r2[1] + r2[2] + r2[3]) * (1.f / 1024.f);
        float m4 = (r4[0] + r4[1] + r4[2] + r4[3]) * (1.f / 1024.f);
        float kurt = m4 / (m2 * m2 + 1e-6f) - 3.f;
        if (kurt > 0.f) atomicAdd(outk, kurt);
    }
}

// ---------------- ropevt: reduce qkv split-K partials + RoPE scatter + V transpose ----------------
__global__ __launch_bounds__(256) void ropevt_kernel(const unsigned short* __restrict__ qkvp,
                                                     unsigned short* __restrict__ qb,
                                                     unsigned short* __restrict__ kb,
                                                     unsigned short* __restrict__ vt) {
    __shared__ float sv[32], cv[32];
    __shared__ unsigned short tile[64][68];
    const size_t Z = (size_t)NTOK * 2048;
    int id = blockIdx.x;
    int tid = threadIdx.x;
    if (id < NTOK) {
        int tok = id;
        int b = tok >> 11, t = tok & 2047;
        if (tid < 32) {
            float fr = (float)tid * (1.f / 32.f);
            float freq = powf(1e6f, -fr);
            float a = (float)t * freq;
            sv[tid] = sinf(a);
            cv[tid] = cosf(a);
        }
        __syncthreads();
        const unsigned short* r0 = qkvp + (size_t)tok * 2048;
        const unsigned short* r1 = r0 + Z;
#pragma unroll
        for (int e = tid; e < 1536; e += 256) {
            int u = e >> 6, d = e & 63;
            int col = (u < 16) ? (u * 64 + d) : (1024 + (u - 16) * 64 + d);
            int pcol = (d < 32) ? col + 32 : col - 32;
            float sgn = (d < 32) ? -1.f : 1.f;
            float vc = bf2f(r0[col]) + bf2f(r1[col]);
            float vp = bf2f(r0[pcol]) + bf2f(r1[pcol]);
            float o = vc * cv[d & 31] + sgn * vp * sv[d & 31];
            if (u < 16)
                qb[((size_t)(b * 16 + u) * 2048 + t) * 64 + d] = f2bf(o);
            else
                kb[((size_t)(b * 8 + (u - 16)) * 2048 + t) * 64 + d] = f2bf(o);
        }
    } else {
        int lid = id - NTOK;
        int b = lid >> 8, h = (lid >> 5) & 7, t0 = (lid & 31) * 64;
        int d = tid & 63, tr = tid >> 6;
#pragma unroll
        for (int i = 0; i < 16; i++) {
            int t = tr + i * 4;
            size_t gi = (size_t)(b * 2048 + t0 + t) * 2048 + 1536 + h * 64 + d;
            tile[t][d] = f2bf(bf2f(qkvp[gi]) + bf2f(qkvp[gi + Z]));
        }
        __syncthreads();
        int tt = tid & 63, dr = tid >> 6;
#pragma unroll
        for (int i = 0; i < 16; i++) {
            int dd = dr + i * 4;
            vt[((size_t)(b * 8 + h) * 64 + dd) * 2048 + t0 + tt] = tile[tt][dd];
        }
    }
}

// ---------------- flash attention: LDS-staged K/V (coalesced), 64-key steps ----------------
// Ks/Vs rows are 128B, stored with 16B-chunk XOR swizzle (chunk_phys = chunk_log ^ (row&7))
// so fragment ds_read_b128 distributes 8 lanes per 4-bank group (conflict-free).
__global__ __launch_bounds__(256) void attn_kernel(const unsigned short* __restrict__ qb,
                                                   const unsigned short* __restrict__ kb,
                                                   const unsigned short* __restrict__ vt,
                                                   unsigned short* __restrict__ ctx) {
    __shared__ __align__(16) unsigned short Ks[64 * 64];   // [key][dim], swizzled
    __shared__ __align__(16) unsigned short Vs[64 * 64];   // [dim][key], swizzled
    __shared__ __align__(16) unsigned short P[4][2][16 * 64];
    const int tid = threadIdx.x, lane = tid & 63, w = tid >> 6;
    const int quad = lane >> 4, l15 = lane & 15;
    const int qt = blockIdx.x, H = blockIdx.y, b = blockIdx.z;
    const int hkv = H & 7;
    const int qw = qt * 64 + w * 16;

    const unsigned short* qbase = qb + ((size_t)(b * 16 + H) * 2048 + qw) * 64;
    short8 aq0 = *(const short8*)(qbase + (size_t)l15 * 64 + quad * 8);
    short8 aq1 = *(const short8*)(qbase + (size_t)l15 * 64 + 32 + quad * 8);

    const unsigned short* kbase = kb + (size_t)(b * 8 + hkv) * 2048 * 64;
    const unsigned short* vbase = vt + (size_t)(b * 8 + hkv) * 64 * 2048;

    const short bf1 = (short)0x3F80;   // bf16 1.0
    const short8 ones = {bf1, bf1, bf1, bf1, bf1, bf1, bf1, bf1};

    f32x4 O[4];
#pragma unroll
    for (int i = 0; i < 4; i++) O[i] = f32x4{0.f, 0.f, 0.f, 0.f};
    f32x4 lacc = f32x4{0.f, 0.f, 0.f, 0.f};

    // staging lane mapping: 8 rows x 8 chunks per wave-issue, chunk XOR-swizzled on global side
    const int srow = lane >> 3;                 // 0..7
    const int schunk = (lane & 7) ^ srow;       // logical 16B chunk to fetch
    const int sw = l15 & 7;                     // read-side swizzle

    int kstartB = qt * 64 - 511;
    if (kstartB < 0) kstartB = 0;
    kstartB &= ~63;
    const int kendB = qt * 64 + 63;
    int buf = 0;

    for (int k0 = kstartB; k0 <= kendB; k0 += 64) {
#pragma unroll
        for (int rr = 0; rr < 2; rr++) {
            int row = w * 8 + rr * 32 + srow;   // 0..63 across waves+rounds
            load_lds16(kbase + (size_t)(k0 + row) * 64 + schunk * 8,
                       &Ks[(w * 8 + rr * 32) * 64]);
            load_lds16(vbase + (size_t)row * 2048 + k0 + schunk * 8,
                       &Vs[(w * 8 + rr * 32) * 64]);
        }
        __syncthreads();
        f32x4 S[4];
#pragma unroll
        for (int c = 0; c < 4; c++) {
            const unsigned short* kp = &Ks[(c * 16 + l15) * 64];
            short8 kf0 = *(const short8*)&kp[(quad ^ sw) * 8];
            short8 kf1 = *(const short8*)&kp[((4 + quad) ^ sw) * 8];
            f32x4 s = __builtin_amdgcn_mfma_f32_16x16x32_bf16(aq0, kf0, f32x4{0.f, 0.f, 0.f, 0.f}, 0, 0, 0);
            s = __builtin_amdgcn_mfma_f32_16x16x32_bf16(aq1, kf1, s, 0, 0, 0);
            S[c] = s;
        }
        unsigned short* Pw = P[w][buf];
#pragma unroll
        for (int c = 0; c < 4; c++)
#pragma unroll
            for (int r = 0; r < 4; r++) {
                int i = qw + quad * 4 + r;
                int j = k0 + c * 16 + l15;
                // p = exp(50*tanh(S*0.0025)); tanh via exp + rcp
                float Sc = fminf(3200.f, fmaxf(-3200.f, S[c][r]));
                float e = __expf(Sc * 0.005f);
                float y = 50.f - 100.f * fastrcp(e + 1.f);
                bool ok = (j <= i) && ((i - j) < 512);
                float pv = ok ? __expf(y) : 0.f;
                Pw[(quad * 4 + r) * 64 + c * 16 + l15] = f2bf(pv);
            }
        asm volatile("s_waitcnt lgkmcnt(0)" ::: "memory");
        short8 pf0 = *(const short8*)&Pw[l15 * 64 + quad * 8];
        short8 pf1 = *(const short8*)&Pw[l15 * 64 + 32 + quad * 8];
#pragma unroll
        for (int ni = 0; ni < 4; ni++) {
            const unsigned short* vp = &Vs[(ni * 16 + l15) * 64];
            short8 vf0 = *(const short8*)&vp[(quad ^ sw) * 8];
            short8 vf1 = *(const short8*)&vp[((4 + quad) ^ sw) * 8];
            O[ni] = __builtin_amdgcn_mfma_f32_16x16x32_bf16(pf0, vf0, O[ni], 0, 0, 0);
            O[ni] = __builtin_amdgcn_mfma_f32_16x16x32_bf16(pf1, vf1, O[ni], 0, 0, 0);
        }
        lacc = __builtin_amdgcn_mfma_f32_16x16x32_bf16(pf0, ones, lacc, 0, 0, 0);
        lacc = __builtin_amdgcn_mfma_f32_16x16x32_bf16(pf1, ones, lacc, 0, 0, 0);
        buf ^= 1;
        __syncthreads();
    }
#pragma unroll
    for (int r = 0; r < 4; r++) {
        float inv = fastrcp(lacc[r]);
        int i = qw + quad * 4 + r;
        size_t tok = (size_t)b * 2048 + i;
#pragma unroll
        for (int ni = 0; ni < 4; ni++)
            ctx[tok * 1024 + H * 64 + ni * 16 + l15] = f2bf(O[ni][r] * inv);
    }
}

// ---------------- launch ----------------
extern "C" void kernel_launch(void* const* d_in, const int* in_sizes, int n_in,
                              void* d_out, int out_size, void* d_ws, size_t ws_size,
                              hipStream_t stream) {
    const float* x = (const float*)d_in[0];
    const float* ksum = (const float*)d_in[1];
    const float* rms1_scale = (const float*)d_in[2];
    const float* q_w = (const float*)d_in[3];
    const float* k_w = (const float*)d_in[4];
    const float* v_w = (const float*)d_in[5];
    const float* out_w = (const float*)d_in[6];
    const float* rms2_scale = (const float*)d_in[7];
    const float* gate_w = (const float*)d_in[8];
    const float* up_w = (const float*)d_in[9];
    const float* down_w = (const float*)d_in[10];

    char* ws = (char*)d_ws;
    unsigned short* wqkv = (unsigned short*)(ws + OFF_WQKV);
    unsigned short* wout = (unsigned short*)(ws + OFF_WOUT);
    unsigned char* wgate = (unsigned char*)(ws + OFF_WGATE);
    unsigned char* wup = (unsigned char*)(ws + OFF_WUP);
    unsigned char* wdown = (unsigned char*)(ws + OFF_WDOWN);
    unsigned short* xn1 = (unsigned short*)(ws + OFF_XN1);
    unsigned short* qkvp = (unsigned short*)(ws + OFF_QKVP);
    unsigned short* p2 = (unsigned short*)(ws + OFF_P2);
    unsigned short* qb = (unsigned short*)(ws + OFF_QB);
    unsigned short* kb = (unsigned short*)(ws + OFF_KB);
    unsigned short* vtb = (unsigned short*)(ws + OFF_VT);
    unsigned short* ctx = (unsigned short*)(ws + OFF_CTX);
    float* x2 = (float*)(ws + OFF_X2);
    unsigned char* xn2 = (unsigned char*)(ws + OFF_XN2);
    unsigned char* g = (unsigned char*)(ws + OFF_G);
    unsigned short* p4 = (unsigned short*)(ws + OFF_P4);
    float* outx = (float*)d_out;
    float* outk = outx + (size_t)NTOK * C;

    // prep: weight transpose+cast (bf16 qkv/out, fp8 x16 mlp) + rms1
    prep_kernel<<<15360 + NTOK, 256, 0, stream>>>(
        q_w, k_w, v_w, out_w, gate_w, up_w, down_w,
        wqkv, wout, wgate, wup, wdown, x, rms1_scale, xn1);

    // QKV projection, split-K=2 -> bf16 partials 2x[4096][2048]
    gemm128<<<dim3(2048 / 128, NTOK / 128, 2), 256, 0, stream>>>(
        xn1, wqkv, qkvp, 2048, 512, 1024, 1024, 512, 512, (size_t)NTOK * 2048);

    // partial-sum + RoPE scatter + V transpose
    ropevt_kernel<<<NTOK + 512, 256, 0, stream>>>(qkvp, qb, kb, vtb);

    // attention (LDS-staged K/V)
    attn_kernel<<<dim3(T / 64, NH, Bsz), 256, 0, stream>>>(qb, kb, vtb, ctx);

    // out projection, split-K=4 bf16 partials, then fused residual+rms2(fp8 x4)+kurt init
    gemm128<<<dim3(1024 / 128, NTOK / 128, 4), 256, 0, stream>>>(
        ctx, wout, p2, 1024, 256, 1024, 1024, 256, 256, (size_t)NTOK * 1024);
    reduce_out<<<NTOK, 256, 0, stream>>>(p2, x, rms2_scale, x2, xn2, ksum, outk);

    // fused gate+up fp8 MX -> g = fp8(silu(gate)*up * 8)
    gateup_kernel<<<dim3(HID / 64, NTOK / 128), 256, 0, stream>>>(xn2, wgate, wup, g);

    // down projection fp8 MX, split-K=4 bf16 partials, then fused residual+kurtosis
    down_gemm<<<dim3(1024 / 128, NTOK / 128, 4), 256, 0, stream>>>(g, wdown, p4);
    reduce_down<<<NTOK, 256, 0, stream>>>(p4, x2, outx, outk);

    (void)in_sizes; (void)n_in; (void)out_size; (void)ws_size;
}